// Round 1
// baseline (551.737 us; speedup 1.0000x reference)
//
#include <hip/hip_runtime.h>

#define M_NODES 50000
#define E_EDGES 600000

typedef short bf16x8 __attribute__((ext_vector_type(8)));
typedef float f32x4 __attribute__((ext_vector_type(4)));

__device__ __forceinline__ unsigned short f2bf(float f){
  unsigned u = __float_as_uint(f);
  u += 0x7FFFu + ((u >> 16) & 1u);
  return (unsigned short)(u >> 16);
}
__device__ __forceinline__ float bf2f(unsigned short h){
  return __uint_as_float(((unsigned)h) << 16);
}

// ---------- split fp32 -> bf16 hi/lo ----------
__global__ __launch_bounds__(256) void k_split(const float* __restrict__ X,
    unsigned short* __restrict__ Xh, unsigned short* __restrict__ Xl, int n4){
  int i = blockIdx.x*256 + threadIdx.x;
  if (i >= n4) return;
  const float4 v = reinterpret_cast<const float4*>(X)[i];
  ushort4 hh, ll;
  hh.x = f2bf(v.x); ll.x = f2bf(v.x - bf2f(hh.x));
  hh.y = f2bf(v.y); ll.y = f2bf(v.y - bf2f(hh.y));
  hh.z = f2bf(v.z); ll.z = f2bf(v.z - bf2f(hh.z));
  hh.w = f2bf(v.w); ll.w = f2bf(v.w - bf2f(hh.w));
  reinterpret_cast<ushort4*>(Xh)[i] = hh;
  reinterpret_cast<ushort4*>(Xl)[i] = ll;
}

// ---------- weight prep: stack [ws;wn] (each [128][N]) -> transposed split [N][256] ----------
__global__ __launch_bounds__(256) void k_prep_w2(const float* __restrict__ Wa,
    const float* __restrict__ Wb, unsigned short* __restrict__ Th,
    unsigned short* __restrict__ Tl){
  int i = blockIdx.x*256 + threadIdx.x;   // 128*256
  if (i >= 128*256) return;
  int n = i >> 8, k = i & 255;
  float v = (k < 128) ? Wa[k*128 + n] : Wb[(k-128)*128 + n];
  unsigned short hi = f2bf(v);
  Th[n*256 + k] = hi;
  Tl[n*256 + k] = f2bf(v - bf2f(hi));
}

// ---------- weight prep: [128][N] -> transposed split [N][128] ----------
__global__ __launch_bounds__(256) void k_prep_w1(const float* __restrict__ W,
    unsigned short* __restrict__ Th, unsigned short* __restrict__ Tl, int N){
  int i = blockIdx.x*256 + threadIdx.x;  // N*128
  if (i >= N*128) return;
  int n = i >> 7, k = i & 127;
  float v = W[k*N + n];
  unsigned short hi = f2bf(v);
  Th[n*128 + k] = hi;
  Tl[n*128 + k] = f2bf(v - bf2f(hi));
}

// ---------- degree histogram ----------
__global__ __launch_bounds__(256) void k_hist(const int* __restrict__ dst, int* __restrict__ cnt){
  int e = blockIdx.x*256 + threadIdx.x;
  if (e < E_EDGES) atomicAdd(&cnt[dst[e]], 1);
}

// ---------- exclusive scan of cnt -> row_ptr (single block, 16-wave shfl scan) ----------
__global__ __launch_bounds__(1024) void k_scan(const int* __restrict__ cnt, int* __restrict__ rp){
  __shared__ int wsum[16];
  __shared__ int carry_s;
  int tid = threadIdx.x, lane = tid & 63, w = tid >> 6;
  if (tid == 0){ rp[0] = 0; carry_s = 0; }
  __syncthreads();
  for (int base = 0; base < M_NODES; base += 1024){
    int i = base + tid;
    int v = (i < M_NODES) ? cnt[i] : 0;
    int x = v;
    #pragma unroll
    for (int off = 1; off < 64; off <<= 1){
      int y = __shfl_up(x, off);
      if (lane >= off) x += y;
    }
    if (lane == 63) wsum[w] = x;
    __syncthreads();
    int c = carry_s;
    int wpre = 0;
    #pragma unroll
    for (int j = 0; j < 16; j++) if (j < w) wpre += wsum[j];
    if (i < M_NODES) rp[i+1] = c + wpre + x;
    __syncthreads();
    if (tid == 0){
      int tot = 0;
      #pragma unroll
      for (int j = 0; j < 16; j++) tot += wsum[j];
      carry_s = c + tot;
    }
    __syncthreads();
  }
}

// ---------- CSR fill ----------
__global__ __launch_bounds__(256) void k_fill(const int* __restrict__ src,
    const int* __restrict__ dst, const int* __restrict__ rp,
    int* __restrict__ cur, int* __restrict__ col){
  int e = blockIdx.x*256 + threadIdx.x;
  if (e >= E_EDGES) return;
  int d = dst[e];
  int pos = rp[d] + atomicAdd(&cur[d], 1);
  col[pos] = src[e];
}

// ---------- mean aggregation: one wave per node, lanes own 2 columns ----------
__global__ __launch_bounds__(256) void k_agg(const unsigned short* __restrict__ Xh,
    const unsigned short* __restrict__ Xl, const int* __restrict__ rp,
    const int* __restrict__ col, unsigned short* __restrict__ Gh,
    unsigned short* __restrict__ Gl){
  int v = blockIdx.x*4 + (threadIdx.x >> 6);
  int lane = threadIdx.x & 63;
  if (v >= M_NODES) return;
  int beg = rp[v], end = rp[v+1];
  float a0 = 0.f, a1 = 0.f;
  for (int e = beg; e < end; e++){
    int s = col[e];
    unsigned hh = *reinterpret_cast<const unsigned*>(Xh + s*128 + lane*2);
    unsigned ll = *reinterpret_cast<const unsigned*>(Xl + s*128 + lane*2);
    a0 += __uint_as_float(hh << 16) + __uint_as_float(ll << 16);
    a1 += __uint_as_float(hh & 0xFFFF0000u) + __uint_as_float(ll & 0xFFFF0000u);
  }
  float inv = 1.f / fmaxf((float)(end - beg), 1.f);
  a0 *= inv; a1 *= inv;
  unsigned short h0 = f2bf(a0), h1 = f2bf(a1);
  unsigned short l0 = f2bf(a0 - bf2f(h0)), l1 = f2bf(a1 - bf2f(h1));
  *reinterpret_cast<unsigned*>(Gh + v*128 + lane*2) = (unsigned)h0 | ((unsigned)h1 << 16);
  *reinterpret_cast<unsigned*>(Gl + v*128 + lane*2) = (unsigned)l0 | ((unsigned)l1 << 16);
}

// ---------- GEMM: Y[M,N] = relu?([A1|A2][M,KL] @ Wt^T + bias), bf16x3 split ----------
// Wt layout: [N][KL] (pre-transposed). Virtual K = 3*KL: v0 Ah*Wh, v1 Al*Wh, v2 Ah*Wl.
template<int KL, int NT, bool RELU, bool WSPLIT, bool WF32>
__global__ __launch_bounds__(256) void k_gemm(
    const unsigned short* __restrict__ A1h, const unsigned short* __restrict__ A1l,
    const unsigned short* __restrict__ A2h, const unsigned short* __restrict__ A2l,
    const unsigned short* __restrict__ Wh, const unsigned short* __restrict__ Wl,
    const float* __restrict__ bias,
    unsigned short* __restrict__ Yh, unsigned short* __restrict__ Yl,
    float* __restrict__ Yf){
  constexpr int NOUT = NT * 16;
  __shared__ __align__(16) unsigned short sA[64*64];
  __shared__ __align__(16) unsigned short sB[128*64];
  const int tid = threadIdx.x;
  const int wave = tid >> 6, lane = tid & 63;
  const int blockRow = blockIdx.x * 64;
  f32x4 acc[NT];
  #pragma unroll
  for (int i = 0; i < NT; i++)
    #pragma unroll
    for (int r = 0; r < 4; r++) acc[i][r] = 0.f;
  constexpr int KC = KL / 64;
  for (int c = 0; c < 3*KC; c++){
    const int vvar = c / KC;
    const int kc = (c % KC) * 64;
    const unsigned short* Ah_ = (kc < 128) ? A1h : A2h;
    const unsigned short* Al_ = (kc < 128) ? A1l : A2l;
    const unsigned short* Asrc = (vvar == 1) ? Al_ : Ah_;
    const unsigned short* Wsrc = (vvar == 2) ? Wl : Wh;
    const int acol = (kc < 128) ? kc : kc - 128;
    __syncthreads();
    {  // stage A: 64 rows x 64 k, XOR-swizzled
      const int row = tid >> 2;
      const int s0 = tid & 3;
      const int grow = blockRow + row;
      #pragma unroll
      for (int i = 0; i < 2; i++){
        const int s = s0 + i*4;
        uint4 val = {0u,0u,0u,0u};
        if (grow < M_NODES)
          val = *reinterpret_cast<const uint4*>(Asrc + grow*128 + acol + s*8);
        *reinterpret_cast<uint4*>(reinterpret_cast<char*>(sA) + row*128 + ((s*16) ^ ((row & 7) << 4))) = val;
      }
    }
    if constexpr (NT == 8){  // stage B: 128 n x 64 k
      const int n = tid >> 1;
      const int sb = (tid & 1) * 4;
      #pragma unroll
      for (int i = 0; i < 4; i++){
        const int s = sb + i;
        *reinterpret_cast<uint4*>(reinterpret_cast<char*>(sB) + n*128 + ((s*16) ^ ((n & 7) << 4))) =
            *reinterpret_cast<const uint4*>(Wsrc + n*KL + kc + s*8);
      }
    } else {                 // NT==4: 64 n x 64 k
      const int n = tid >> 2;
      const int s0 = tid & 3;
      #pragma unroll
      for (int i = 0; i < 2; i++){
        const int s = s0 + i*4;
        *reinterpret_cast<uint4*>(reinterpret_cast<char*>(sB) + n*128 + ((s*16) ^ ((n & 7) << 4))) =
            *reinterpret_cast<const uint4*>(Wsrc + n*KL + kc + s*8);
      }
    }
    __syncthreads();
    const int arow = wave*16 + (lane & 15);
    #pragma unroll
    for (int ks = 0; ks < 2; ks++){
      const int kk2 = (ks*32 + ((lane >> 4) * 8)) * 2;   // byte offset of k
      bf16x8 af = *reinterpret_cast<const bf16x8*>(
          reinterpret_cast<const char*>(sA) + arow*128 + (kk2 ^ ((arow & 7) << 4)));
      #pragma unroll
      for (int nt = 0; nt < NT; nt++){
        const int n = nt*16 + (lane & 15);
        bf16x8 bfr = *reinterpret_cast<const bf16x8*>(
            reinterpret_cast<const char*>(sB) + n*128 + (kk2 ^ ((n & 7) << 4)));
        acc[nt] = __builtin_amdgcn_mfma_f32_16x16x32_bf16(af, bfr, acc[nt], 0, 0, 0);
      }
    }
  }
  // epilogue: D row = (lane>>4)*4 + r, col = lane&15 (m89-verified layout)
  const int r0 = (lane >> 4) * 4;
  const int grow0 = blockRow + wave*16 + r0;
  #pragma unroll
  for (int nt = 0; nt < NT; nt++){
    const int colx = nt*16 + (lane & 15);
    const float bsv = bias[colx];
    #pragma unroll
    for (int r = 0; r < 4; r++){
      const int grow = grow0 + r;
      if (grow < M_NODES){
        float vv = acc[nt][r] + bsv;
        if (RELU) vv = fmaxf(vv, 0.f);
        if constexpr (WSPLIT){
          unsigned short hi = f2bf(vv);
          unsigned short lo = f2bf(vv - bf2f(hi));
          Yh[grow*NOUT + colx] = hi;
          Yl[grow*NOUT + colx] = lo;
        }
        if constexpr (WF32) Yf[grow*NOUT + colx] = vv;
      }
    }
  }
}

// ---------- graph-id histogram (wave-aggregated; gid is sorted) ----------
__global__ __launch_bounds__(256) void k_hist_gid(const int* __restrict__ gid, int* __restrict__ gcnt){
  int i = blockIdx.x*256 + threadIdx.x;
  bool valid = i < M_NODES;
  int g = valid ? gid[i] : -1;
  int g0 = __shfl(g, 0);
  if (__all(g == g0)){
    if ((threadIdx.x & 63) == 0 && valid) atomicAdd(&gcnt[g], 64);
  } else if (valid){
    atomicAdd(&gcnt[g], 1);
  }
}

// ---------- per-graph mean pool (sorted gid -> contiguous ranges) ----------
__global__ __launch_bounds__(256) void k_pool(const float* __restrict__ Xf,
    const int* __restrict__ gcnt, float* __restrict__ out){
  const int g = blockIdx.x;
  const int tid = threadIdx.x, w = tid >> 6, lane = tid & 63;
  __shared__ int sstart;
  __shared__ float part[4][64];
  if (w == 0){
    int v = gcnt[lane];
    int x = v;
    #pragma unroll
    for (int off = 1; off < 64; off <<= 1){
      int y = __shfl_up(x, off);
      if (lane >= off) x += y;
    }
    if (lane == g) sstart = x - v;   // exclusive prefix at g
  }
  __syncthreads();
  const int start = sstart;
  const int cg = gcnt[g];
  float a = 0.f;
  for (int j = w; j < cg; j += 4)
    a += Xf[(size_t)(start + j)*64 + lane];
  part[w][lane] = a;
  __syncthreads();
  if (w == 0){
    float s = part[0][lane] + part[1][lane] + part[2][lane] + part[3][lane];
    out[g*64 + lane] = s / fmaxf((float)cg, 1.f);
  }
}

extern "C" void kernel_launch(void* const* d_in, const int* in_sizes, int n_in,
                              void* d_out, int out_size, void* d_ws, size_t ws_size,
                              hipStream_t stream){
  const float* h    = (const float*)d_in[0];
  const int*   esrc = (const int*)d_in[1];
  const int*   edst = (const int*)d_in[2];
  const int*   gid  = (const int*)d_in[3];
  const float* ws0  = (const float*)d_in[4];
  const float* wn0  = (const float*)d_in[5];
  const float* bs0  = (const float*)d_in[6];
  const float* ws1  = (const float*)d_in[7];
  const float* wn1  = (const float*)d_in[8];
  const float* bs1  = (const float*)d_in[9];
  const float* ws2  = (const float*)d_in[10];
  const float* wn2  = (const float*)d_in[11];
  const float* bs2  = (const float*)d_in[12];
  const float* lw0  = (const float*)d_in[13];
  const float* lb0  = (const float*)d_in[14];
  const float* lw1  = (const float*)d_in[15];
  const float* lb1  = (const float*)d_in[16];
  const float* lw2  = (const float*)d_in[17];
  const float* lb2  = (const float*)d_in[18];
  float* out = (float*)d_out;

  char* p = (char*)d_ws;
  auto alloc = [&](size_t b)->char*{ char* r = p; p += (b + 255) & ~(size_t)255; return r; };
  unsigned short* X0h = (unsigned short*)alloc((size_t)M_NODES*128*2);
  unsigned short* X0l = (unsigned short*)alloc((size_t)M_NODES*128*2);
  unsigned short* XBh = (unsigned short*)alloc((size_t)M_NODES*128*2);
  unsigned short* XBl = (unsigned short*)alloc((size_t)M_NODES*128*2);
  unsigned short* Gh  = (unsigned short*)alloc((size_t)M_NODES*128*2);
  unsigned short* Gl  = (unsigned short*)alloc((size_t)M_NODES*128*2);
  float* xF = (float*)alloc((size_t)M_NODES*64*4);
  char* zbase = p;                       // contiguous zero-init region
  int* cnt  = (int*)alloc((size_t)M_NODES*4);
  int* cur  = (int*)alloc((size_t)M_NODES*4);
  int* gcnt = (int*)alloc(256);
  size_t zbytes = (size_t)(p - zbase);
  int* rp   = (int*)alloc((size_t)(M_NODES+1)*4);
  int* col  = (int*)alloc((size_t)E_EDGES*4);
  unsigned short* W0h = (unsigned short*)alloc(128*256*2);
  unsigned short* W0l = (unsigned short*)alloc(128*256*2);
  unsigned short* W1h = (unsigned short*)alloc(128*256*2);
  unsigned short* W1l = (unsigned short*)alloc(128*256*2);
  unsigned short* W2h = (unsigned short*)alloc(128*256*2);
  unsigned short* W2l = (unsigned short*)alloc(128*256*2);
  unsigned short* L0h = (unsigned short*)alloc(128*128*2);
  unsigned short* L0l = (unsigned short*)alloc(128*128*2);
  unsigned short* L1h = (unsigned short*)alloc(128*128*2);
  unsigned short* L1l = (unsigned short*)alloc(128*128*2);
  unsigned short* L2h = (unsigned short*)alloc(64*128*2);
  unsigned short* L2l = (unsigned short*)alloc(64*128*2);

  hipMemsetAsync(zbase, 0, zbytes, stream);
  k_split<<<(M_NODES*128/4 + 255)/256, 256, 0, stream>>>(h, X0h, X0l, M_NODES*128/4);
  k_prep_w2<<<128, 256, 0, stream>>>(ws0, wn0, W0h, W0l);
  k_prep_w2<<<128, 256, 0, stream>>>(ws1, wn1, W1h, W1l);
  k_prep_w2<<<128, 256, 0, stream>>>(ws2, wn2, W2h, W2l);
  k_prep_w1<<<64, 256, 0, stream>>>(lw0, L0h, L0l, 128);
  k_prep_w1<<<64, 256, 0, stream>>>(lw1, L1h, L1l, 128);
  k_prep_w1<<<32, 256, 0, stream>>>(lw2, L2h, L2l, 64);
  k_hist<<<(E_EDGES+255)/256, 256, 0, stream>>>(edst, cnt);
  k_scan<<<1, 1024, 0, stream>>>(cnt, rp);
  k_fill<<<(E_EDGES+255)/256, 256, 0, stream>>>(esrc, edst, rp, cur, col);
  k_hist_gid<<<(M_NODES+255)/256, 256, 0, stream>>>(gid, gcnt);

  const int gGrid = (M_NODES + 63)/64;
  // SAGE layer 0 (relu)
  k_agg<<<(M_NODES+3)/4, 256, 0, stream>>>(X0h, X0l, rp, col, Gh, Gl);
  k_gemm<256,8,true,true,false><<<gGrid,256,0,stream>>>(X0h,X0l,Gh,Gl,W0h,W0l,bs0,XBh,XBl,nullptr);
  // SAGE layer 1 (relu)
  k_agg<<<(M_NODES+3)/4, 256, 0, stream>>>(XBh, XBl, rp, col, Gh, Gl);
  k_gemm<256,8,true,true,false><<<gGrid,256,0,stream>>>(XBh,XBl,Gh,Gl,W1h,W1l,bs1,X0h,X0l,nullptr);
  // SAGE layer 2 (no relu)
  k_agg<<<(M_NODES+3)/4, 256, 0, stream>>>(X0h, X0l, rp, col, Gh, Gl);
  k_gemm<256,8,false,true,false><<<gGrid,256,0,stream>>>(X0h,X0l,Gh,Gl,W2h,W2l,bs2,XBh,XBl,nullptr);
  // MLP
  k_gemm<128,8,true,true,false><<<gGrid,256,0,stream>>>(XBh,XBl,XBh,XBl,L0h,L0l,lb0,X0h,X0l,nullptr);
  k_gemm<128,8,true,true,false><<<gGrid,256,0,stream>>>(X0h,X0l,X0h,X0l,L1h,L1l,lb1,XBh,XBl,nullptr);
  k_gemm<128,4,false,false,true><<<gGrid,256,0,stream>>>(XBh,XBl,XBh,XBl,L2h,L2l,lb2,nullptr,nullptr,xF);
  // pooling
  k_pool<<<64, 256, 0, stream>>>(xF, gcnt, out);
}

// Round 2
// 457.069 us; speedup vs baseline: 1.2071x; 1.2071x over previous
//
#include <hip/hip_runtime.h>

#define M_NODES 50000
#define E_EDGES 600000
#define SCAN_B ((M_NODES + 255) / 256)

typedef short bf16x8 __attribute__((ext_vector_type(8)));
typedef float f32x4 __attribute__((ext_vector_type(4)));

__device__ __forceinline__ unsigned short f2bf(float f){
  unsigned u = __float_as_uint(f);
  u += 0x7FFFu + ((u >> 16) & 1u);
  return (unsigned short)(u >> 16);
}
__device__ __forceinline__ float bf2f(unsigned short h){
  return __uint_as_float(((unsigned)h) << 16);
}

// ---------- weight prep: stack [ws;wn] (each [128][N]) -> transposed split [N][256] ----------
__global__ __launch_bounds__(256) void k_prep_w2(const float* __restrict__ Wa,
    const float* __restrict__ Wb, unsigned short* __restrict__ Th,
    unsigned short* __restrict__ Tl){
  int i = blockIdx.x*256 + threadIdx.x;   // 128*256
  if (i >= 128*256) return;
  int n = i >> 8, k = i & 255;
  float v = (k < 128) ? Wa[k*128 + n] : Wb[(k-128)*128 + n];
  unsigned short hi = f2bf(v);
  Th[n*256 + k] = hi;
  Tl[n*256 + k] = f2bf(v - bf2f(hi));
}

// ---------- weight prep: [128][N] -> transposed split [N][128] ----------
__global__ __launch_bounds__(256) void k_prep_w1(const float* __restrict__ W,
    unsigned short* __restrict__ Th, unsigned short* __restrict__ Tl, int N){
  int i = blockIdx.x*256 + threadIdx.x;  // N*128
  if (i >= N*128) return;
  int n = i >> 7, k = i & 127;
  float v = W[k*N + n];
  unsigned short hi = f2bf(v);
  Th[n*128 + k] = hi;
  Tl[n*128 + k] = f2bf(v - bf2f(hi));
}

// ---------- degree histogram ----------
__global__ __launch_bounds__(256) void k_hist(const int* __restrict__ dst, int* __restrict__ cnt){
  int e = blockIdx.x*256 + threadIdx.x;
  if (e < E_EDGES) atomicAdd(&cnt[dst[e]], 1);
}

// ---------- 3-phase exclusive scan of cnt -> rp ----------
__global__ __launch_bounds__(256) void k_scan1(const int* __restrict__ cnt,
    int* __restrict__ rp, int* __restrict__ bsum){
  __shared__ int wsum[4];
  int b = blockIdx.x, tid = threadIdx.x, lane = tid & 63, w = tid >> 6;
  int i = b*256 + tid;
  int v = (i < M_NODES) ? cnt[i] : 0;
  int x = v;
  #pragma unroll
  for (int off = 1; off < 64; off <<= 1){
    int y = __shfl_up(x, off);
    if (lane >= off) x += y;
  }
  if (lane == 63) wsum[w] = x;
  __syncthreads();
  int pre = 0;
  #pragma unroll
  for (int j = 0; j < 4; j++) if (j < w) pre += wsum[j];
  if (i < M_NODES) rp[i+1] = pre + x;
  if (tid == 255) bsum[b] = pre + x;
}

__global__ __launch_bounds__(256) void k_scan2(const int* __restrict__ bsum, int* __restrict__ boff){
  __shared__ int wsum[4];
  int tid = threadIdx.x, lane = tid & 63, w = tid >> 6;
  int v = (tid < SCAN_B) ? bsum[tid] : 0;
  int x = v;
  #pragma unroll
  for (int off = 1; off < 64; off <<= 1){
    int y = __shfl_up(x, off);
    if (lane >= off) x += y;
  }
  if (lane == 63) wsum[w] = x;
  __syncthreads();
  int pre = 0;
  #pragma unroll
  for (int j = 0; j < 4; j++) if (j < w) pre += wsum[j];
  if (tid < SCAN_B) boff[tid] = pre + x - v;
}

__global__ __launch_bounds__(256) void k_scan3(int* __restrict__ rp, const int* __restrict__ boff){
  int b = blockIdx.x, tid = threadIdx.x;
  int i = b*256 + tid;
  if (i == 0) rp[0] = 0;
  if (i < M_NODES) rp[i+1] += boff[b];
}

// ---------- CSR fill ----------
__global__ __launch_bounds__(256) void k_fill(const int* __restrict__ src,
    const int* __restrict__ dst, const int* __restrict__ rp,
    int* __restrict__ cur, int* __restrict__ col){
  int e = blockIdx.x*256 + threadIdx.x;
  if (e >= E_EDGES) return;
  int d = dst[e];
  int pos = rp[d] + atomicAdd(&cur[d], 1);
  col[pos] = src[e];
}

// ---------- mean aggregation: one wave per node, fp32 rows, 2-wide unrolled ----------
__global__ __launch_bounds__(256) void k_agg(const float* __restrict__ X,
    const int* __restrict__ rp, const int* __restrict__ col, float* __restrict__ G){
  int v = blockIdx.x*4 + (threadIdx.x >> 6);
  int lane = threadIdx.x & 63;
  if (v >= M_NODES) return;
  int beg = rp[v], end = rp[v+1];
  float a0 = 0.f, a1 = 0.f, b0 = 0.f, b1 = 0.f;
  int e = beg;
  for (; e + 2 <= end; e += 2){
    int s0 = col[e], s1 = col[e+1];
    float2 v0 = *reinterpret_cast<const float2*>(X + (size_t)s0*128 + lane*2);
    float2 v1 = *reinterpret_cast<const float2*>(X + (size_t)s1*128 + lane*2);
    a0 += v0.x; a1 += v0.y;
    b0 += v1.x; b1 += v1.y;
  }
  if (e < end){
    float2 v0 = *reinterpret_cast<const float2*>(X + (size_t)col[e]*128 + lane*2);
    a0 += v0.x; a1 += v0.y;
  }
  a0 += b0; a1 += b1;
  float inv = 1.f / fmaxf((float)(end - beg), 1.f);
  float2 r; r.x = a0*inv; r.y = a1*inv;
  *reinterpret_cast<float2*>(G + (size_t)v*128 + lane*2) = r;
}

// ---------- GEMM: Y[M,NOUT] = relu?([A1|A2] @ W^T + bias), fp32 in/out, bf16x3 split in LDS ----------
template<int KL, int NT, bool RELU>
__global__ __launch_bounds__(256) void k_gemm(
    const float* __restrict__ A1, const float* __restrict__ A2,
    const unsigned short* __restrict__ Wh, const unsigned short* __restrict__ Wl,
    const float* __restrict__ bias, float* __restrict__ Y){
  constexpr int NOUT = NT * 16;
  constexpr int KC = KL / 64;
  __shared__ __align__(16) unsigned short sAh[64*64];
  __shared__ __align__(16) unsigned short sAl[64*64];
  __shared__ __align__(16) unsigned short sBh[NOUT*64];
  __shared__ __align__(16) unsigned short sBl[NOUT*64];
  const int tid = threadIdx.x;
  const int wave = tid >> 6, lane = tid & 63;
  const int blockRow = blockIdx.x * 64;
  f32x4 acc[NT];
  #pragma unroll
  for (int i = 0; i < NT; i++)
    #pragma unroll
    for (int r = 0; r < 4; r++) acc[i][r] = 0.f;

  for (int kc = 0; kc < KC; kc++){
    const float* Asrc; int acol;
    if (KL == 256 && kc >= 2){ Asrc = A2; acol = (kc - 2)*64; }
    else                     { Asrc = A1; acol = kc*64; }
    __syncthreads();
    {  // stage A: 64 rows x 64 cols fp32 -> hi/lo bf16 tiles (XOR-swizzled rows)
      const int row = tid >> 2, q = tid & 3;
      const int grow = blockRow + row;
      const float* ap = Asrc + (size_t)grow*128 + acol + q*16;
      #pragma unroll
      for (int i = 0; i < 4; i++){
        float4 f;
        if (grow < M_NODES) f = *reinterpret_cast<const float4*>(ap + i*4);
        else { f.x = 0.f; f.y = 0.f; f.z = 0.f; f.w = 0.f; }
        ushort4 hh, ll;
        hh.x = f2bf(f.x); ll.x = f2bf(f.x - bf2f(hh.x));
        hh.y = f2bf(f.y); ll.y = f2bf(f.y - bf2f(hh.y));
        hh.z = f2bf(f.z); ll.z = f2bf(f.z - bf2f(hh.z));
        hh.w = f2bf(f.w); ll.w = f2bf(f.w - bf2f(hh.w));
        const int byt = (q*32 + i*8) ^ ((row & 7) << 4);
        *reinterpret_cast<ushort4*>(reinterpret_cast<char*>(sAh) + row*128 + byt) = hh;
        *reinterpret_cast<ushort4*>(reinterpret_cast<char*>(sAl) + row*128 + byt) = ll;
      }
    }
    {  // stage B: NOUT rows x 64 cols, hi+lo
      constexpr int TPR = 256 / NOUT;   // threads per row
      constexpr int SPT = 8 / TPR;      // 16B slots per thread
      const int n = tid / TPR, part = tid % TPR;
      const unsigned short* wph = Wh + n*KL + kc*64;
      const unsigned short* wpl = Wl + n*KL + kc*64;
      #pragma unroll
      for (int i = 0; i < SPT; i++){
        const int s = part*SPT + i;
        const int byt = (s*16) ^ ((n & 7) << 4);
        *reinterpret_cast<uint4*>(reinterpret_cast<char*>(sBh) + n*128 + byt) =
            *reinterpret_cast<const uint4*>(wph + s*8);
        *reinterpret_cast<uint4*>(reinterpret_cast<char*>(sBl) + n*128 + byt) =
            *reinterpret_cast<const uint4*>(wpl + s*8);
      }
    }
    __syncthreads();
    const int arow = wave*16 + (lane & 15);
    #pragma unroll
    for (int ks = 0; ks < 2; ks++){
      const int kb = (ks*32 + ((lane >> 4) * 8)) * 2;
      bf16x8 ah = *reinterpret_cast<const bf16x8*>(
          reinterpret_cast<const char*>(sAh) + arow*128 + (kb ^ ((arow & 7) << 4)));
      bf16x8 al = *reinterpret_cast<const bf16x8*>(
          reinterpret_cast<const char*>(sAl) + arow*128 + (kb ^ ((arow & 7) << 4)));
      #pragma unroll
      for (int nt = 0; nt < NT; nt++){
        const int n = nt*16 + (lane & 15);
        bf16x8 bh = *reinterpret_cast<const bf16x8*>(
            reinterpret_cast<const char*>(sBh) + n*128 + (kb ^ ((n & 7) << 4)));
        bf16x8 bl = *reinterpret_cast<const bf16x8*>(
            reinterpret_cast<const char*>(sBl) + n*128 + (kb ^ ((n & 7) << 4)));
        acc[nt] = __builtin_amdgcn_mfma_f32_16x16x32_bf16(ah, bh, acc[nt], 0, 0, 0);
        acc[nt] = __builtin_amdgcn_mfma_f32_16x16x32_bf16(al, bh, acc[nt], 0, 0, 0);
        acc[nt] = __builtin_amdgcn_mfma_f32_16x16x32_bf16(ah, bl, acc[nt], 0, 0, 0);
      }
    }
  }
  // epilogue: D row = (lane>>4)*4 + r, col = lane&15
  const int r0 = (lane >> 4) * 4;
  const int grow0 = blockRow + wave*16 + r0;
  #pragma unroll
  for (int nt = 0; nt < NT; nt++){
    const int colx = nt*16 + (lane & 15);
    const float bsv = bias[colx];
    #pragma unroll
    for (int r = 0; r < 4; r++){
      const int grow = grow0 + r;
      if (grow < M_NODES){
        float vv = acc[nt][r] + bsv;
        if (RELU) vv = fmaxf(vv, 0.f);
        Y[(size_t)grow*NOUT + colx] = vv;
      }
    }
  }
}

// ---------- graph-id histogram (wave-aggregated; gid is sorted) ----------
__global__ __launch_bounds__(256) void k_hist_gid(const int* __restrict__ gid, int* __restrict__ gcnt){
  int i = blockIdx.x*256 + threadIdx.x;
  bool valid = i < M_NODES;
  int g = valid ? gid[i] : -1;
  int g0 = __shfl(g, 0);
  if (__all(g == g0)){
    if ((threadIdx.x & 63) == 0 && valid) atomicAdd(&gcnt[g], 64);
  } else if (valid){
    atomicAdd(&gcnt[g], 1);
  }
}

// ---------- per-graph mean pool (sorted gid -> contiguous ranges) ----------
__global__ __launch_bounds__(256) void k_pool(const float* __restrict__ Xf,
    const int* __restrict__ gcnt, float* __restrict__ out){
  const int g = blockIdx.x;
  const int tid = threadIdx.x, w = tid >> 6, lane = tid & 63;
  __shared__ int sstart;
  __shared__ float part[4][64];
  if (w == 0){
    int v = gcnt[lane];
    int x = v;
    #pragma unroll
    for (int off = 1; off < 64; off <<= 1){
      int y = __shfl_up(x, off);
      if (lane >= off) x += y;
    }
    if (lane == g) sstart = x - v;
  }
  __syncthreads();
  const int start = sstart;
  const int cg = gcnt[g];
  float a = 0.f;
  for (int j = w; j < cg; j += 4)
    a += Xf[(size_t)(start + j)*64 + lane];
  part[w][lane] = a;
  __syncthreads();
  if (w == 0){
    float s = part[0][lane] + part[1][lane] + part[2][lane] + part[3][lane];
    out[g*64 + lane] = s / fmaxf((float)cg, 1.f);
  }
}

extern "C" void kernel_launch(void* const* d_in, const int* in_sizes, int n_in,
                              void* d_out, int out_size, void* d_ws, size_t ws_size,
                              hipStream_t stream){
  const float* h    = (const float*)d_in[0];
  const int*   esrc = (const int*)d_in[1];
  const int*   edst = (const int*)d_in[2];
  const int*   gid  = (const int*)d_in[3];
  const float* ws0  = (const float*)d_in[4];
  const float* wn0  = (const float*)d_in[5];
  const float* bs0  = (const float*)d_in[6];
  const float* ws1  = (const float*)d_in[7];
  const float* wn1  = (const float*)d_in[8];
  const float* bs1  = (const float*)d_in[9];
  const float* ws2  = (const float*)d_in[10];
  const float* wn2  = (const float*)d_in[11];
  const float* bs2  = (const float*)d_in[12];
  const float* lw0  = (const float*)d_in[13];
  const float* lb0  = (const float*)d_in[14];
  const float* lw1  = (const float*)d_in[15];
  const float* lb1  = (const float*)d_in[16];
  const float* lw2  = (const float*)d_in[17];
  const float* lb2  = (const float*)d_in[18];
  float* out = (float*)d_out;

  char* p = (char*)d_ws;
  auto alloc = [&](size_t b)->char*{ char* r = p; p += (b + 255) & ~(size_t)255; return r; };
  float* XA = (float*)alloc((size_t)M_NODES*128*4);
  float* XB = (float*)alloc((size_t)M_NODES*128*4);
  float* G  = (float*)alloc((size_t)M_NODES*128*4);
  float* xF = (float*)alloc((size_t)M_NODES*64*4);
  char* zbase = p;                       // contiguous zero-init region
  int* cnt  = (int*)alloc((size_t)M_NODES*4);
  int* cur  = (int*)alloc((size_t)M_NODES*4);
  int* gcnt = (int*)alloc(256);
  size_t zbytes = (size_t)(p - zbase);
  int* rp   = (int*)alloc((size_t)(M_NODES+1)*4);
  int* col  = (int*)alloc((size_t)E_EDGES*4);
  int* bsum = (int*)alloc((size_t)SCAN_B*4);
  int* boff = (int*)alloc((size_t)SCAN_B*4);
  unsigned short* W0h = (unsigned short*)alloc(128*256*2);
  unsigned short* W0l = (unsigned short*)alloc(128*256*2);
  unsigned short* W1h = (unsigned short*)alloc(128*256*2);
  unsigned short* W1l = (unsigned short*)alloc(128*256*2);
  unsigned short* W2h = (unsigned short*)alloc(128*256*2);
  unsigned short* W2l = (unsigned short*)alloc(128*256*2);
  unsigned short* L0h = (unsigned short*)alloc(128*128*2);
  unsigned short* L0l = (unsigned short*)alloc(128*128*2);
  unsigned short* L1h = (unsigned short*)alloc(128*128*2);
  unsigned short* L1l = (unsigned short*)alloc(128*128*2);
  unsigned short* L2h = (unsigned short*)alloc(64*128*2);
  unsigned short* L2l = (unsigned short*)alloc(64*128*2);

  hipMemsetAsync(zbase, 0, zbytes, stream);
  k_prep_w2<<<128, 256, 0, stream>>>(ws0, wn0, W0h, W0l);
  k_prep_w2<<<128, 256, 0, stream>>>(ws1, wn1, W1h, W1l);
  k_prep_w2<<<128, 256, 0, stream>>>(ws2, wn2, W2h, W2l);
  k_prep_w1<<<64, 256, 0, stream>>>(lw0, L0h, L0l, 128);
  k_prep_w1<<<64, 256, 0, stream>>>(lw1, L1h, L1l, 128);
  k_prep_w1<<<32, 256, 0, stream>>>(lw2, L2h, L2l, 64);
  k_hist<<<(E_EDGES+255)/256, 256, 0, stream>>>(edst, cnt);
  k_scan1<<<SCAN_B, 256, 0, stream>>>(cnt, rp, bsum);
  k_scan2<<<1, 256, 0, stream>>>(bsum, boff);
  k_scan3<<<SCAN_B, 256, 0, stream>>>(rp, boff);
  k_fill<<<(E_EDGES+255)/256, 256, 0, stream>>>(esrc, edst, rp, cur, col);
  k_hist_gid<<<(M_NODES+255)/256, 256, 0, stream>>>(gid, gcnt);

  const int gGrid = (M_NODES + 63)/64;
  // SAGE layer 0 (relu)
  k_agg<<<(M_NODES+3)/4, 256, 0, stream>>>(h, rp, col, G);
  k_gemm<256,8,true ><<<gGrid,256,0,stream>>>(h,  G, W0h, W0l, bs0, XA);
  // SAGE layer 1 (relu)
  k_agg<<<(M_NODES+3)/4, 256, 0, stream>>>(XA, rp, col, G);
  k_gemm<256,8,true ><<<gGrid,256,0,stream>>>(XA, G, W1h, W1l, bs1, XB);
  // SAGE layer 2 (no relu)
  k_agg<<<(M_NODES+3)/4, 256, 0, stream>>>(XB, rp, col, G);
  k_gemm<256,8,false><<<gGrid,256,0,stream>>>(XB, G, W2h, W2l, bs2, XA);
  // MLP
  k_gemm<128,8,true ><<<gGrid,256,0,stream>>>(XA, nullptr, L0h, L0l, lb0, XB);
  k_gemm<128,8,true ><<<gGrid,256,0,stream>>>(XB, nullptr, L1h, L1l, lb1, XA);
  k_gemm<128,4,false><<<gGrid,256,0,stream>>>(XA, nullptr, L2h, L2l, lb2, xF);
  // pooling
  k_pool<<<64, 256, 0, stream>>>(xF, gcnt, out);
}

// Round 3
// 403.185 us; speedup vs baseline: 1.3684x; 1.1336x over previous
//
#include <hip/hip_runtime.h>

#define M_NODES 50000
#define E_EDGES 600000
#define SCAN_B ((M_NODES + 255) / 256)

typedef short bf16x8 __attribute__((ext_vector_type(8)));
typedef float f32x4 __attribute__((ext_vector_type(4)));

__device__ __forceinline__ unsigned short f2bf(float f){
  unsigned u = __float_as_uint(f);
  u += 0x7FFFu + ((u >> 16) & 1u);
  return (unsigned short)(u >> 16);
}
__device__ __forceinline__ float bf2f(unsigned short h){
  return __uint_as_float(((unsigned)h) << 16);
}

// ---------- weight prep: stack [ws;wn] (each [128][N]) -> transposed split [N][256] ----------
__global__ __launch_bounds__(256) void k_prep_w2(const float* __restrict__ Wa,
    const float* __restrict__ Wb, unsigned short* __restrict__ Th,
    unsigned short* __restrict__ Tl){
  int i = blockIdx.x*256 + threadIdx.x;   // 128*256
  if (i >= 128*256) return;
  int n = i >> 8, k = i & 255;
  float v = (k < 128) ? Wa[k*128 + n] : Wb[(k-128)*128 + n];
  unsigned short hi = f2bf(v);
  Th[n*256 + k] = hi;
  Tl[n*256 + k] = f2bf(v - bf2f(hi));
}

// ---------- weight prep: [128][N] -> transposed split [N][128] ----------
__global__ __launch_bounds__(256) void k_prep_w1(const float* __restrict__ W,
    unsigned short* __restrict__ Th, unsigned short* __restrict__ Tl, int N){
  int i = blockIdx.x*256 + threadIdx.x;  // N*128
  if (i >= N*128) return;
  int n = i >> 7, k = i & 127;
  float v = W[k*N + n];
  unsigned short hi = f2bf(v);
  Th[n*128 + k] = hi;
  Tl[n*128 + k] = f2bf(v - bf2f(hi));
}

// ---------- degree histogram ----------
__global__ __launch_bounds__(256) void k_hist(const int* __restrict__ dst, int* __restrict__ cnt){
  int e = blockIdx.x*256 + threadIdx.x;
  if (e < E_EDGES) atomicAdd(&cnt[dst[e]], 1);
}

// ---------- 3-phase exclusive scan of cnt -> rp ----------
__global__ __launch_bounds__(256) void k_scan1(const int* __restrict__ cnt,
    int* __restrict__ rp, int* __restrict__ bsum){
  __shared__ int wsum[4];
  int b = blockIdx.x, tid = threadIdx.x, lane = tid & 63, w = tid >> 6;
  int i = b*256 + tid;
  int v = (i < M_NODES) ? cnt[i] : 0;
  int x = v;
  #pragma unroll
  for (int off = 1; off < 64; off <<= 1){
    int y = __shfl_up(x, off);
    if (lane >= off) x += y;
  }
  if (lane == 63) wsum[w] = x;
  __syncthreads();
  int pre = 0;
  #pragma unroll
  for (int j = 0; j < 4; j++) if (j < w) pre += wsum[j];
  if (i < M_NODES) rp[i+1] = pre + x;
  if (tid == 255) bsum[b] = pre + x;
}

__global__ __launch_bounds__(256) void k_scan2(const int* __restrict__ bsum, int* __restrict__ boff){
  __shared__ int wsum[4];
  int tid = threadIdx.x, lane = tid & 63, w = tid >> 6;
  int v = (tid < SCAN_B) ? bsum[tid] : 0;
  int x = v;
  #pragma unroll
  for (int off = 1; off < 64; off <<= 1){
    int y = __shfl_up(x, off);
    if (lane >= off) x += y;
  }
  if (lane == 63) wsum[w] = x;
  __syncthreads();
  int pre = 0;
  #pragma unroll
  for (int j = 0; j < 4; j++) if (j < w) pre += wsum[j];
  if (tid < SCAN_B) boff[tid] = pre + x - v;
}

__global__ __launch_bounds__(256) void k_scan3(int* __restrict__ rp, const int* __restrict__ boff){
  int b = blockIdx.x, tid = threadIdx.x;
  int i = b*256 + tid;
  if (i == 0) rp[0] = 0;
  if (i < M_NODES) rp[i+1] += boff[b];
}

// ---------- CSR fill ----------
__global__ __launch_bounds__(256) void k_fill(const int* __restrict__ src,
    const int* __restrict__ dst, const int* __restrict__ rp,
    int* __restrict__ cur, int* __restrict__ col){
  int e = blockIdx.x*256 + threadIdx.x;
  if (e >= E_EDGES) return;
  int d = dst[e];
  int pos = rp[d] + atomicAdd(&cur[d], 1);
  col[pos] = src[e];
}

// ---------- mean aggregation: half-wave per node (float4 lanes), 2-edge unroll ----------
__global__ __launch_bounds__(256) void k_agg(const float* __restrict__ X,
    const int* __restrict__ rp, const int* __restrict__ col, float* __restrict__ G){
  const int w = threadIdx.x >> 6;
  const int hf = (threadIdx.x >> 5) & 1;
  const int hl = threadIdx.x & 31;
  const int v = blockIdx.x*8 + w*2 + hf;
  if (v >= M_NODES) return;
  const int beg = rp[v], end = rp[v+1];
  float4 A = {0.f,0.f,0.f,0.f}, B = {0.f,0.f,0.f,0.f};
  int e = beg;
  for (; e + 2 <= end; e += 2){
    const int s0 = col[e], s1 = col[e+1];
    const float4 x0 = *reinterpret_cast<const float4*>(X + (size_t)s0*128 + hl*4);
    const float4 x1 = *reinterpret_cast<const float4*>(X + (size_t)s1*128 + hl*4);
    A.x += x0.x; A.y += x0.y; A.z += x0.z; A.w += x0.w;
    B.x += x1.x; B.y += x1.y; B.z += x1.z; B.w += x1.w;
  }
  if (e < end){
    const float4 x0 = *reinterpret_cast<const float4*>(X + (size_t)col[e]*128 + hl*4);
    A.x += x0.x; A.y += x0.y; A.z += x0.z; A.w += x0.w;
  }
  const float inv = 1.f / fmaxf((float)(end - beg), 1.f);
  float4 r;
  r.x = (A.x + B.x)*inv; r.y = (A.y + B.y)*inv;
  r.z = (A.z + B.z)*inv; r.w = (A.w + B.w)*inv;
  *reinterpret_cast<float4*>(G + (size_t)v*128 + hl*4) = r;
}

// ---------- GEMM: Y[M,NOUT] = relu?([A1|A2] @ W^T + bias), 128-row tiles, bf16x3 in LDS ----------
template<int KL, int NT, bool RELU>
__global__ __launch_bounds__(256) void k_gemm(
    const float* __restrict__ A1, const float* __restrict__ A2,
    const unsigned short* __restrict__ Wh, const unsigned short* __restrict__ Wl,
    const float* __restrict__ bias, float* __restrict__ Y){
  constexpr int NOUT = NT * 16;
  constexpr int KC = KL / 64;
  __shared__ __align__(16) unsigned short sAh[128*64];
  __shared__ __align__(16) unsigned short sAl[128*64];
  __shared__ __align__(16) unsigned short sBh[NOUT*64];
  __shared__ __align__(16) unsigned short sBl[NOUT*64];
  const int tid = threadIdx.x;
  const int wave = tid >> 6, lane = tid & 63;
  const int blockRow = blockIdx.x * 128;
  f32x4 acc[2][NT];
  #pragma unroll
  for (int a = 0; a < 2; a++)
    #pragma unroll
    for (int i = 0; i < NT; i++)
      #pragma unroll
      for (int r = 0; r < 4; r++) acc[a][i][r] = 0.f;

  for (int kc = 0; kc < KC; kc++){
    const float* Asrc; int acol;
    if (KL == 256 && kc >= 2){ Asrc = A2; acol = (kc - 2)*64; }
    else                     { Asrc = A1; acol = kc*64; }
    __syncthreads();
    {  // stage A: 128 rows x 64 cols fp32 -> hi/lo bf16 (XOR-swizzled)
      const int row = tid >> 1, part = tid & 1;
      const int grow = blockRow + row;
      const float* ap = Asrc + (size_t)grow*128 + acol + part*32;
      #pragma unroll
      for (int i = 0; i < 8; i++){
        float4 f;
        if (grow < M_NODES) f = *reinterpret_cast<const float4*>(ap + i*4);
        else { f.x = 0.f; f.y = 0.f; f.z = 0.f; f.w = 0.f; }
        ushort4 hh, ll;
        hh.x = f2bf(f.x); ll.x = f2bf(f.x - bf2f(hh.x));
        hh.y = f2bf(f.y); ll.y = f2bf(f.y - bf2f(hh.y));
        hh.z = f2bf(f.z); ll.z = f2bf(f.z - bf2f(hh.z));
        hh.w = f2bf(f.w); ll.w = f2bf(f.w - bf2f(hh.w));
        const int byt = (part*64 + i*8) ^ ((row & 7) << 4);
        *reinterpret_cast<ushort4*>(reinterpret_cast<char*>(sAh) + row*128 + byt) = hh;
        *reinterpret_cast<ushort4*>(reinterpret_cast<char*>(sAl) + row*128 + byt) = ll;
      }
    }
    {  // stage B: NOUT rows x 64 cols, hi+lo
      constexpr int TPR = 256 / NOUT;   // threads per row
      constexpr int SPT = 8 / TPR;      // 16B slots per thread
      const int n = tid / TPR, part = tid % TPR;
      const unsigned short* wph = Wh + n*KL + kc*64;
      const unsigned short* wpl = Wl + n*KL + kc*64;
      #pragma unroll
      for (int i = 0; i < SPT; i++){
        const int s = part*SPT + i;
        const int byt = (s*16) ^ ((n & 7) << 4);
        *reinterpret_cast<uint4*>(reinterpret_cast<char*>(sBh) + n*128 + byt) =
            *reinterpret_cast<const uint4*>(wph + s*8);
        *reinterpret_cast<uint4*>(reinterpret_cast<char*>(sBl) + n*128 + byt) =
            *reinterpret_cast<const uint4*>(wpl + s*8);
      }
    }
    __syncthreads();
    #pragma unroll
    for (int ks = 0; ks < 2; ks++){
      const int kb = (ks*32 + ((lane >> 4) * 8)) * 2;
      bf16x8 ah[2], al[2];
      #pragma unroll
      for (int ar = 0; ar < 2; ar++){
        const int arow = wave*32 + ar*16 + (lane & 15);
        ah[ar] = *reinterpret_cast<const bf16x8*>(
            reinterpret_cast<const char*>(sAh) + arow*128 + (kb ^ ((arow & 7) << 4)));
        al[ar] = *reinterpret_cast<const bf16x8*>(
            reinterpret_cast<const char*>(sAl) + arow*128 + (kb ^ ((arow & 7) << 4)));
      }
      #pragma unroll
      for (int nt = 0; nt < NT; nt++){
        const int n = nt*16 + (lane & 15);
        bf16x8 bh = *reinterpret_cast<const bf16x8*>(
            reinterpret_cast<const char*>(sBh) + n*128 + (kb ^ ((n & 7) << 4)));
        bf16x8 bl = *reinterpret_cast<const bf16x8*>(
            reinterpret_cast<const char*>(sBl) + n*128 + (kb ^ ((n & 7) << 4)));
        #pragma unroll
        for (int ar = 0; ar < 2; ar++){
          acc[ar][nt] = __builtin_amdgcn_mfma_f32_16x16x32_bf16(ah[ar], bh, acc[ar][nt], 0, 0, 0);
          acc[ar][nt] = __builtin_amdgcn_mfma_f32_16x16x32_bf16(al[ar], bh, acc[ar][nt], 0, 0, 0);
          acc[ar][nt] = __builtin_amdgcn_mfma_f32_16x16x32_bf16(ah[ar], bl, acc[ar][nt], 0, 0, 0);
        }
      }
    }
  }
  // epilogue: D row = (lane>>4)*4 + r, col = lane&15
  const int r0 = (lane >> 4) * 4;
  #pragma unroll
  for (int ar = 0; ar < 2; ar++){
    const int grow0 = blockRow + wave*32 + ar*16 + r0;
    #pragma unroll
    for (int nt = 0; nt < NT; nt++){
      const int colx = nt*16 + (lane & 15);
      const float bsv = bias[colx];
      #pragma unroll
      for (int r = 0; r < 4; r++){
        const int grow = grow0 + r;
        if (grow < M_NODES){
          float vv = acc[ar][nt][r] + bsv;
          if (RELU) vv = fmaxf(vv, 0.f);
          Y[(size_t)grow*NOUT + colx] = vv;
        }
      }
    }
  }
}

// ---------- graph-id histogram (wave-aggregated; gid is sorted) ----------
__global__ __launch_bounds__(256) void k_hist_gid(const int* __restrict__ gid, int* __restrict__ gcnt){
  int i = blockIdx.x*256 + threadIdx.x;
  bool valid = i < M_NODES;
  int g = valid ? gid[i] : -1;
  int g0 = __shfl(g, 0);
  if (__all(g == g0)){
    if ((threadIdx.x & 63) == 0 && valid) atomicAdd(&gcnt[g], 64);
  } else if (valid){
    atomicAdd(&gcnt[g], 1);
  }
}

// ---------- pooling stage 1: 8 sub-chunks per graph, 512 blocks ----------
__global__ __launch_bounds__(256) void k_pool1(const float* __restrict__ Xf,
    const int* __restrict__ gcnt, float* __restrict__ pp){
  const int g = blockIdx.x >> 3, s = blockIdx.x & 7;
  const int tid = threadIdx.x, w = tid >> 6, lane = tid & 63;
  __shared__ int sstart;
  __shared__ float part[4][64];
  if (w == 0){
    int v = gcnt[lane];
    int x = v;
    #pragma unroll
    for (int off = 1; off < 64; off <<= 1){
      int y = __shfl_up(x, off);
      if (lane >= off) x += y;
    }
    if (lane == g) sstart = x - v;
  }
  __syncthreads();
  const int cg = gcnt[g];
  const int Lc = (cg + 7) >> 3;
  const int nbeg = sstart + s*Lc;
  const int nend = min(nbeg + Lc, sstart + cg);
  float a0 = 0.f, a1 = 0.f;
  int i = nbeg + w;
  for (; i + 4 < nend; i += 8){
    a0 += Xf[(size_t)i*64 + lane];
    a1 += Xf[(size_t)(i+4)*64 + lane];
  }
  if (i < nend) a0 += Xf[(size_t)i*64 + lane];
  part[w][lane] = a0 + a1;
  __syncthreads();
  if (w == 0)
    pp[(size_t)(g*8 + s)*64 + lane] = part[0][lane] + part[1][lane] + part[2][lane] + part[3][lane];
}

// ---------- pooling stage 2 ----------
__global__ __launch_bounds__(64) void k_pool2(const float* __restrict__ pp,
    const int* __restrict__ gcnt, float* __restrict__ out){
  const int g = blockIdx.x, lane = threadIdx.x;
  float sum = 0.f;
  #pragma unroll
  for (int s = 0; s < 8; s++) sum += pp[(size_t)(g*8 + s)*64 + lane];
  out[g*64 + lane] = sum / fmaxf((float)gcnt[g], 1.f);
}

extern "C" void kernel_launch(void* const* d_in, const int* in_sizes, int n_in,
                              void* d_out, int out_size, void* d_ws, size_t ws_size,
                              hipStream_t stream){
  const float* h    = (const float*)d_in[0];
  const int*   esrc = (const int*)d_in[1];
  const int*   edst = (const int*)d_in[2];
  const int*   gid  = (const int*)d_in[3];
  const float* ws0  = (const float*)d_in[4];
  const float* wn0  = (const float*)d_in[5];
  const float* bs0  = (const float*)d_in[6];
  const float* ws1  = (const float*)d_in[7];
  const float* wn1  = (const float*)d_in[8];
  const float* bs1  = (const float*)d_in[9];
  const float* ws2  = (const float*)d_in[10];
  const float* wn2  = (const float*)d_in[11];
  const float* bs2  = (const float*)d_in[12];
  const float* lw0  = (const float*)d_in[13];
  const float* lb0  = (const float*)d_in[14];
  const float* lw1  = (const float*)d_in[15];
  const float* lb1  = (const float*)d_in[16];
  const float* lw2  = (const float*)d_in[17];
  const float* lb2  = (const float*)d_in[18];
  float* out = (float*)d_out;

  char* p = (char*)d_ws;
  auto alloc = [&](size_t b)->char*{ char* r = p; p += (b + 255) & ~(size_t)255; return r; };
  float* XA = (float*)alloc((size_t)M_NODES*128*4);
  float* XB = (float*)alloc((size_t)M_NODES*128*4);
  float* G  = (float*)alloc((size_t)M_NODES*128*4);
  float* xF = (float*)alloc((size_t)M_NODES*64*4);
  float* pp = (float*)alloc((size_t)64*8*64*4);
  char* zbase = p;                       // contiguous zero-init region
  int* cnt  = (int*)alloc((size_t)M_NODES*4);
  int* cur  = (int*)alloc((size_t)M_NODES*4);
  int* gcnt = (int*)alloc(256);
  size_t zbytes = (size_t)(p - zbase);
  int* rp   = (int*)alloc((size_t)(M_NODES+1)*4);
  int* col  = (int*)alloc((size_t)E_EDGES*4);
  int* bsum = (int*)alloc((size_t)SCAN_B*4);
  int* boff = (int*)alloc((size_t)SCAN_B*4);
  unsigned short* W0h = (unsigned short*)alloc(128*256*2);
  unsigned short* W0l = (unsigned short*)alloc(128*256*2);
  unsigned short* W1h = (unsigned short*)alloc(128*256*2);
  unsigned short* W1l = (unsigned short*)alloc(128*256*2);
  unsigned short* W2h = (unsigned short*)alloc(128*256*2);
  unsigned short* W2l = (unsigned short*)alloc(128*256*2);
  unsigned short* L0h = (unsigned short*)alloc(128*128*2);
  unsigned short* L0l = (unsigned short*)alloc(128*128*2);
  unsigned short* L1h = (unsigned short*)alloc(128*128*2);
  unsigned short* L1l = (unsigned short*)alloc(128*128*2);
  unsigned short* L2h = (unsigned short*)alloc(64*128*2);
  unsigned short* L2l = (unsigned short*)alloc(64*128*2);

  hipMemsetAsync(zbase, 0, zbytes, stream);
  k_prep_w2<<<128, 256, 0, stream>>>(ws0, wn0, W0h, W0l);
  k_prep_w2<<<128, 256, 0, stream>>>(ws1, wn1, W1h, W1l);
  k_prep_w2<<<128, 256, 0, stream>>>(ws2, wn2, W2h, W2l);
  k_prep_w1<<<64, 256, 0, stream>>>(lw0, L0h, L0l, 128);
  k_prep_w1<<<64, 256, 0, stream>>>(lw1, L1h, L1l, 128);
  k_prep_w1<<<32, 256, 0, stream>>>(lw2, L2h, L2l, 64);
  k_hist<<<(E_EDGES+255)/256, 256, 0, stream>>>(edst, cnt);
  k_scan1<<<SCAN_B, 256, 0, stream>>>(cnt, rp, bsum);
  k_scan2<<<1, 256, 0, stream>>>(bsum, boff);
  k_scan3<<<SCAN_B, 256, 0, stream>>>(rp, boff);
  k_fill<<<(E_EDGES+255)/256, 256, 0, stream>>>(esrc, edst, rp, cur, col);
  k_hist_gid<<<(M_NODES+255)/256, 256, 0, stream>>>(gid, gcnt);

  const int gGrid = (M_NODES + 127)/128;
  const int aGrid = (M_NODES + 7)/8;
  // SAGE layer 0 (relu)
  k_agg<<<aGrid, 256, 0, stream>>>(h, rp, col, G);
  k_gemm<256,8,true ><<<gGrid,256,0,stream>>>(h,  G, W0h, W0l, bs0, XA);
  // SAGE layer 1 (relu)
  k_agg<<<aGrid, 256, 0, stream>>>(XA, rp, col, G);
  k_gemm<256,8,true ><<<gGrid,256,0,stream>>>(XA, G, W1h, W1l, bs1, XB);
  // SAGE layer 2 (no relu)
  k_agg<<<aGrid, 256, 0, stream>>>(XB, rp, col, G);
  k_gemm<256,8,false><<<gGrid,256,0,stream>>>(XB, G, W2h, W2l, bs2, XA);
  // MLP
  k_gemm<128,8,true ><<<gGrid,256,0,stream>>>(XA, nullptr, L0h, L0l, lb0, XB);
  k_gemm<128,8,true ><<<gGrid,256,0,stream>>>(XB, nullptr, L1h, L1l, lb1, XA);
  k_gemm<128,4,false><<<gGrid,256,0,stream>>>(XA, nullptr, L2h, L2l, lb2, xF);
  // pooling
  k_pool1<<<512, 256, 0, stream>>>(xF, gcnt, pp);
  k_pool2<<<64, 64, 0, stream>>>(pp, gcnt, out);
}

// Round 4
// 364.283 us; speedup vs baseline: 1.5146x; 1.1068x over previous
//
#include <hip/hip_runtime.h>

#define M_NODES 50000
#define E_EDGES 600000
#define SCAN_B ((M_NODES + 255) / 256)

typedef short bf16x8 __attribute__((ext_vector_type(8)));
typedef float f32x4 __attribute__((ext_vector_type(4)));

__device__ __forceinline__ unsigned short f2bf(float f){
  unsigned u = __float_as_uint(f);
  u += 0x7FFFu + ((u >> 16) & 1u);
  return (unsigned short)(u >> 16);
}
__device__ __forceinline__ float bf2f(unsigned short h){
  return __uint_as_float(((unsigned)h) << 16);
}
__device__ __forceinline__ unsigned short lob(float x){
  unsigned short h = f2bf(x);
  return f2bf(x - bf2f(h));
}
__device__ __forceinline__ void gl_lds16(const void* g, void* l){
  __builtin_amdgcn_global_load_lds(
      (const __attribute__((address_space(1))) unsigned int*)g,
      (__attribute__((address_space(3))) unsigned int*)l, 16, 0, 0);
}

// ---------- split fp32 h -> split rows [hi128|lo128] ----------
__global__ __launch_bounds__(256) void k_split(const float* __restrict__ H,
    char* __restrict__ X){
  int i = blockIdx.x*256 + threadIdx.x;          // over M*16 granules
  if (i >= M_NODES*16) return;
  int n = i >> 4, j = i & 15;
  const float4 f0 = *reinterpret_cast<const float4*>(H + (size_t)n*128 + j*8);
  const float4 f1 = *reinterpret_cast<const float4*>(H + (size_t)n*128 + j*8 + 4);
  uint4 hq, lq;
  hq.x = (unsigned)f2bf(f0.x) | ((unsigned)f2bf(f0.y) << 16);
  hq.y = (unsigned)f2bf(f0.z) | ((unsigned)f2bf(f0.w) << 16);
  hq.z = (unsigned)f2bf(f1.x) | ((unsigned)f2bf(f1.y) << 16);
  hq.w = (unsigned)f2bf(f1.z) | ((unsigned)f2bf(f1.w) << 16);
  lq.x = (unsigned)lob(f0.x) | ((unsigned)lob(f0.y) << 16);
  lq.y = (unsigned)lob(f0.z) | ((unsigned)lob(f0.w) << 16);
  lq.z = (unsigned)lob(f1.x) | ((unsigned)lob(f1.y) << 16);
  lq.w = (unsigned)lob(f1.z) | ((unsigned)lob(f1.w) << 16);
  *reinterpret_cast<uint4*>(X + (size_t)n*512 + j*16)       = hq;
  *reinterpret_cast<uint4*>(X + (size_t)n*512 + 256 + j*16) = lq;
}

// ---------- all weight preps in one kernel ----------
__global__ __launch_bounds__(256) void k_prep_all(
    const float* __restrict__ ws0, const float* __restrict__ wn0,
    const float* __restrict__ ws1, const float* __restrict__ wn1,
    const float* __restrict__ ws2, const float* __restrict__ wn2,
    const float* __restrict__ lw0, const float* __restrict__ lw1,
    const float* __restrict__ lw2,
    unsigned short* __restrict__ W0h, unsigned short* __restrict__ W0l,
    unsigned short* __restrict__ W1h, unsigned short* __restrict__ W1l,
    unsigned short* __restrict__ W2h, unsigned short* __restrict__ W2l,
    unsigned short* __restrict__ L0h, unsigned short* __restrict__ L0l,
    unsigned short* __restrict__ L1h, unsigned short* __restrict__ L1l,
    unsigned short* __restrict__ L2h, unsigned short* __restrict__ L2l){
  const int b = blockIdx.x, t = threadIdx.x;
  if (b < 384){                      // stacked [ws;wn] -> [N=128][K=256]
    const int wsel = b >> 7;
    const int i = (b & 127)*256 + t;
    const float* Wa = wsel==0?ws0:(wsel==1?ws1:ws2);
    const float* Wb = wsel==0?wn0:(wsel==1?wn1:wn2);
    unsigned short* Th = wsel==0?W0h:(wsel==1?W1h:W2h);
    unsigned short* Tl = wsel==0?W0l:(wsel==1?W1l:W2l);
    int n = i >> 8, k = i & 255;
    float v = (k < 128) ? Wa[k*128 + n] : Wb[(k-128)*128 + n];
    unsigned short hi = f2bf(v);
    Th[n*256 + k] = hi; Tl[n*256 + k] = f2bf(v - bf2f(hi));
  } else if (b < 512){               // lw0/lw1 [128][128] -> [128][128]^T
    const int lsel = (b - 384) >> 6;
    const int i = ((b - 384) & 63)*256 + t;
    const float* W = lsel==0?lw0:lw1;
    unsigned short* Th = lsel==0?L0h:L1h;
    unsigned short* Tl = lsel==0?L0l:L1l;
    int n = i >> 7, k = i & 127;
    float v = W[k*128 + n];
    unsigned short hi = f2bf(v);
    Th[n*128 + k] = hi; Tl[n*128 + k] = f2bf(v - bf2f(hi));
  } else {                           // lw2 [128][64] -> [64][128]^T
    const int i = (b - 512)*256 + t;
    if (i >= 64*128) return;
    int n = i >> 7, k = i & 127;
    float v = lw2[k*64 + n];
    unsigned short hi = f2bf(v);
    L2h[n*128 + k] = hi; L2l[n*128 + k] = f2bf(v - bf2f(hi));
  }
}

// ---------- degree histogram ----------
__global__ __launch_bounds__(256) void k_hist(const int* __restrict__ dst, int* __restrict__ cnt){
  int e = blockIdx.x*256 + threadIdx.x;
  if (e < E_EDGES) atomicAdd(&cnt[dst[e]], 1);
}

// ---------- 3-phase exclusive scan of cnt -> rp ----------
__global__ __launch_bounds__(256) void k_scan1(const int* __restrict__ cnt,
    int* __restrict__ rp, int* __restrict__ bsum){
  __shared__ int wsum[4];
  int b = blockIdx.x, tid = threadIdx.x, lane = tid & 63, w = tid >> 6;
  int i = b*256 + tid;
  int v = (i < M_NODES) ? cnt[i] : 0;
  int x = v;
  #pragma unroll
  for (int off = 1; off < 64; off <<= 1){
    int y = __shfl_up(x, off);
    if (lane >= off) x += y;
  }
  if (lane == 63) wsum[w] = x;
  __syncthreads();
  int pre = 0;
  #pragma unroll
  for (int j = 0; j < 4; j++) if (j < w) pre += wsum[j];
  if (i < M_NODES) rp[i+1] = pre + x;
  if (tid == 255) bsum[b] = pre + x;
}

__global__ __launch_bounds__(256) void k_scan2(const int* __restrict__ bsum, int* __restrict__ boff){
  __shared__ int wsum[4];
  int tid = threadIdx.x, lane = tid & 63, w = tid >> 6;
  int v = (tid < SCAN_B) ? bsum[tid] : 0;
  int x = v;
  #pragma unroll
  for (int off = 1; off < 64; off <<= 1){
    int y = __shfl_up(x, off);
    if (lane >= off) x += y;
  }
  if (lane == 63) wsum[w] = x;
  __syncthreads();
  int pre = 0;
  #pragma unroll
  for (int j = 0; j < 4; j++) if (j < w) pre += wsum[j];
  if (tid < SCAN_B) boff[tid] = pre + x - v;
}

__global__ __launch_bounds__(256) void k_scan3(int* __restrict__ rp, const int* __restrict__ boff){
  int b = blockIdx.x, tid = threadIdx.x;
  int i = b*256 + tid;
  if (i == 0) rp[0] = 0;
  if (i < M_NODES) rp[i+1] += boff[b];
}

// ---------- CSR fill ----------
__global__ __launch_bounds__(256) void k_fill(const int* __restrict__ src,
    const int* __restrict__ dst, const int* __restrict__ rp,
    int* __restrict__ cur, int* __restrict__ col){
  int e = blockIdx.x*256 + threadIdx.x;
  if (e >= E_EDGES) return;
  int d = dst[e];
  int pos = rp[d] + atomicAdd(&cur[d], 1);
  col[pos] = src[e];
}

// ---------- mean aggregation over split rows ----------
#define ACC8(u) \
  a[0] += __uint_as_float((u).x << 16); a[1] += __uint_as_float((u).x & 0xFFFF0000u); \
  a[2] += __uint_as_float((u).y << 16); a[3] += __uint_as_float((u).y & 0xFFFF0000u); \
  a[4] += __uint_as_float((u).z << 16); a[5] += __uint_as_float((u).z & 0xFFFF0000u); \
  a[6] += __uint_as_float((u).w << 16); a[7] += __uint_as_float((u).w & 0xFFFF0000u);

__global__ __launch_bounds__(256) void k_agg(const char* __restrict__ X,
    const int* __restrict__ rp, const int* __restrict__ col, char* __restrict__ G){
  const int w = threadIdx.x >> 6;
  const int hf = (threadIdx.x >> 5) & 1;
  const int hl = threadIdx.x & 31;
  const int v = blockIdx.x*8 + w*2 + hf;
  if (v >= M_NODES) return;
  const int beg = rp[v], end = rp[v+1];
  const int off = hl*16;
  float a[8];
  #pragma unroll
  for (int k = 0; k < 8; k++) a[k] = 0.f;
  int e = beg;
  for (; e + 4 <= end; e += 4){
    const int s0 = col[e], s1 = col[e+1], s2 = col[e+2], s3 = col[e+3];
    const uint4 x0 = *reinterpret_cast<const uint4*>(X + (size_t)s0*512 + off);
    const uint4 x1 = *reinterpret_cast<const uint4*>(X + (size_t)s1*512 + off);
    const uint4 x2 = *reinterpret_cast<const uint4*>(X + (size_t)s2*512 + off);
    const uint4 x3 = *reinterpret_cast<const uint4*>(X + (size_t)s3*512 + off);
    ACC8(x0); ACC8(x1); ACC8(x2); ACC8(x3);
  }
  for (; e < end; e++){
    const uint4 x0 = *reinterpret_cast<const uint4*>(X + (size_t)col[e]*512 + off);
    ACC8(x0);
  }
  const float inv = 1.f / fmaxf((float)(end - beg), 1.f);
  #pragma unroll
  for (int k = 0; k < 8; k++) a[k] = (a[k] + __shfl_xor(a[k], 16)) * inv;
  // lanes hl<16 write hi granule, hl>=16 write lo granule; same addr formula
  unsigned rw[4];
  #pragma unroll
  for (int k = 0; k < 4; k++){
    float x0 = a[2*k], x1 = a[2*k+1];
    unsigned short h0 = f2bf(x0), h1 = f2bf(x1);
    unsigned short l0 = f2bf(x0 - bf2f(h0)), l1 = f2bf(x1 - bf2f(h1));
    rw[k] = (hl < 16) ? ((unsigned)h0 | ((unsigned)h1 << 16))
                      : ((unsigned)l0 | ((unsigned)l1 << 16));
  }
  uint4 q; q.x = rw[0]; q.y = rw[1]; q.z = rw[2]; q.w = rw[3];
  *reinterpret_cast<uint4*>(G + (size_t)v*512 + off) = q;
}

// ---------- GEMM: split-row A (global_load_lds), split W, bf16x3 ----------
template<int KL, int NT, bool RELU, bool SPLITOUT>
__global__ __launch_bounds__(256) void k_gemm(
    const char* __restrict__ A1, const char* __restrict__ A2,
    const unsigned short* __restrict__ Wh, const unsigned short* __restrict__ Wl,
    const float* __restrict__ bias, char* __restrict__ Y){
  constexpr int NOUT = NT * 16;
  constexpr int KC = KL / 64;
  constexpr int NBI = NOUT / 32;           // B stage insts per wave
  __shared__ __align__(16) char sAh[128*128];
  __shared__ __align__(16) char sAl[128*128];
  __shared__ __align__(16) char sBh[NOUT*128];
  __shared__ __align__(16) char sBl[NOUT*128];
  const int tid = threadIdx.x;
  const int wave = tid >> 6, lane = tid & 63;
  const int blockRow = blockIdx.x * 128;
  const int srow = lane >> 3, slot = lane & 7;
  const int sb = (slot*16) ^ (srow << 4);  // inverse-swizzled source granule
  size_t aoff[4];
  #pragma unroll
  for (int i = 0; i < 4; i++){
    int grow = blockRow + wave*32 + i*8 + srow;
    if (grow >= M_NODES) grow = M_NODES - 1;
    aoff[i] = (size_t)grow*512 + sb;
  }
  size_t boff[NBI];
  #pragma unroll
  for (int i = 0; i < NBI; i++){
    int n = wave*(NOUT/4) + i*8 + srow;
    boff[i] = (size_t)n*(2*KL) + sb;
  }
  f32x4 acc[2][NT];
  #pragma unroll
  for (int a = 0; a < 2; a++)
    #pragma unroll
    for (int i = 0; i < NT; i++)
      #pragma unroll
      for (int r = 0; r < 4; r++) acc[a][i][r] = 0.f;

  for (int kc = 0; kc < KC; kc++){
    const char* Ap; int acolb;
    if (KL == 256 && kc >= 2){ Ap = A2; acolb = (kc - 2)*128; }
    else                     { Ap = A1; acolb = kc*128; }
    const int bcolb = kc*128;
    __syncthreads();
    #pragma unroll
    for (int i = 0; i < 4; i++){
      const int lr = (wave*32 + i*8)*128;
      gl_lds16(Ap + aoff[i] + acolb,       sAh + lr);
      gl_lds16(Ap + aoff[i] + acolb + 256, sAl + lr);
    }
    #pragma unroll
    for (int i = 0; i < NBI; i++){
      const int lr = (wave*(NOUT/4) + i*8)*128;
      gl_lds16(reinterpret_cast<const char*>(Wh) + boff[i] + bcolb, sBh + lr);
      gl_lds16(reinterpret_cast<const char*>(Wl) + boff[i] + bcolb, sBl + lr);
    }
    __syncthreads();
    #pragma unroll
    for (int ks = 0; ks < 2; ks++){
      const int kb = (ks*32 + ((lane >> 4) * 8)) * 2;
      bf16x8 ah[2], al[2];
      #pragma unroll
      for (int ar = 0; ar < 2; ar++){
        const int arow = wave*32 + ar*16 + (lane & 15);
        const int ab = arow*128 + (kb ^ ((arow & 7) << 4));
        ah[ar] = *reinterpret_cast<const bf16x8*>(sAh + ab);
        al[ar] = *reinterpret_cast<const bf16x8*>(sAl + ab);
      }
      #pragma unroll
      for (int nt = 0; nt < NT; nt++){
        const int n = nt*16 + (lane & 15);
        const int bb = n*128 + (kb ^ ((n & 7) << 4));
        const bf16x8 bh = *reinterpret_cast<const bf16x8*>(sBh + bb);
        const bf16x8 bl = *reinterpret_cast<const bf16x8*>(sBl + bb);
        #pragma unroll
        for (int ar = 0; ar < 2; ar++){
          acc[ar][nt] = __builtin_amdgcn_mfma_f32_16x16x32_bf16(ah[ar], bh, acc[ar][nt], 0, 0, 0);
          acc[ar][nt] = __builtin_amdgcn_mfma_f32_16x16x32_bf16(al[ar], bh, acc[ar][nt], 0, 0, 0);
          acc[ar][nt] = __builtin_amdgcn_mfma_f32_16x16x32_bf16(ah[ar], bl, acc[ar][nt], 0, 0, 0);
        }
      }
    }
  }
  // epilogue: row = (lane>>4)*4 + r, col = lane&15
  const int r0 = (lane >> 4) * 4;
  #pragma unroll
  for (int ar = 0; ar < 2; ar++){
    const int growb = blockRow + wave*32 + ar*16 + r0;
    #pragma unroll
    for (int nt = 0; nt < NT; nt++){
      const int colx = nt*16 + (lane & 15);
      const float bsv = bias[colx];
      #pragma unroll
      for (int r = 0; r < 4; r++){
        const int grow = growb + r;
        float vv = acc[ar][nt][r] + bsv;
        if (RELU) vv = fmaxf(vv, 0.f);
        if constexpr (SPLITOUT){
          const float vo = __shfl_xor(vv, 1);
          if (grow < M_NODES){
            if ((lane & 1) == 0){
              const unsigned hv = (unsigned)f2bf(vv) | ((unsigned)f2bf(vo) << 16);
              *reinterpret_cast<unsigned*>(Y + (size_t)grow*512 + colx*2) = hv;
            } else {
              const unsigned lv = (unsigned)lob(vo) | ((unsigned)lob(vv) << 16);
              *reinterpret_cast<unsigned*>(Y + (size_t)grow*512 + 256 + (colx-1)*2) = lv;
            }
          }
        } else {
          if (grow < M_NODES)
            *reinterpret_cast<float*>(Y + ((size_t)grow*NOUT + colx)*4) = vv;
        }
      }
    }
  }
}

// ---------- graph-id histogram (wave-aggregated; gid is sorted) ----------
__global__ __launch_bounds__(256) void k_hist_gid(const int* __restrict__ gid, int* __restrict__ gcnt){
  int i = blockIdx.x*256 + threadIdx.x;
  bool valid = i < M_NODES;
  int g = valid ? gid[i] : -1;
  int g0 = __shfl(g, 0);
  if (__all(g == g0)){
    if ((threadIdx.x & 63) == 0 && valid) atomicAdd(&gcnt[g], 64);
  } else if (valid){
    atomicAdd(&gcnt[g], 1);
  }
}

// ---------- pooling stage 1: 8 sub-chunks per graph ----------
__global__ __launch_bounds__(256) void k_pool1(const float* __restrict__ Xf,
    const int* __restrict__ gcnt, float* __restrict__ pp){
  const int g = blockIdx.x >> 3, s = blockIdx.x & 7;
  const int tid = threadIdx.x, w = tid >> 6, lane = tid & 63;
  __shared__ int sstart;
  __shared__ float part[4][64];
  if (w == 0){
    int v = gcnt[lane];
    int x = v;
    #pragma unroll
    for (int off = 1; off < 64; off <<= 1){
      int y = __shfl_up(x, off);
      if (lane >= off) x += y;
    }
    if (lane == g) sstart = x - v;
  }
  __syncthreads();
  const int cg = gcnt[g];
  const int Lc = (cg + 7) >> 3;
  const int nbeg = sstart + s*Lc;
  const int nend = min(nbeg + Lc, sstart + cg);
  float a0 = 0.f, a1 = 0.f;
  int i = nbeg + w;
  for (; i + 4 < nend; i += 8){
    a0 += Xf[(size_t)i*64 + lane];
    a1 += Xf[(size_t)(i+4)*64 + lane];
  }
  if (i < nend) a0 += Xf[(size_t)i*64 + lane];
  part[w][lane] = a0 + a1;
  __syncthreads();
  if (w == 0)
    pp[(size_t)(g*8 + s)*64 + lane] = part[0][lane] + part[1][lane] + part[2][lane] + part[3][lane];
}

// ---------- pooling stage 2 ----------
__global__ __launch_bounds__(64) void k_pool2(const float* __restrict__ pp,
    const int* __restrict__ gcnt, float* __restrict__ out){
  const int g = blockIdx.x, lane = threadIdx.x;
  float sum = 0.f;
  #pragma unroll
  for (int s = 0; s < 8; s++) sum += pp[(size_t)(g*8 + s)*64 + lane];
  out[g*64 + lane] = sum / fmaxf((float)gcnt[g], 1.f);
}

extern "C" void kernel_launch(void* const* d_in, const int* in_sizes, int n_in,
                              void* d_out, int out_size, void* d_ws, size_t ws_size,
                              hipStream_t stream){
  const float* h    = (const float*)d_in[0];
  const int*   esrc = (const int*)d_in[1];
  const int*   edst = (const int*)d_in[2];
  const int*   gid  = (const int*)d_in[3];
  const float* ws0  = (const float*)d_in[4];
  const float* wn0  = (const float*)d_in[5];
  const float* bs0  = (const float*)d_in[6];
  const float* ws1  = (const float*)d_in[7];
  const float* wn1  = (const float*)d_in[8];
  const float* bs1  = (const float*)d_in[9];
  const float* ws2  = (const float*)d_in[10];
  const float* wn2  = (const float*)d_in[11];
  const float* bs2  = (const float*)d_in[12];
  const float* lw0  = (const float*)d_in[13];
  const float* lb0  = (const float*)d_in[14];
  const float* lw1  = (const float*)d_in[15];
  const float* lb1  = (const float*)d_in[16];
  const float* lw2  = (const float*)d_in[17];
  const float* lb2  = (const float*)d_in[18];
  float* out = (float*)d_out;

  char* p = (char*)d_ws;
  auto alloc = [&](size_t b)->char*{ char* r = p; p += (b + 255) & ~(size_t)255; return r; };
  char* X0 = alloc((size_t)M_NODES*512);
  char* XA = alloc((size_t)M_NODES*512);
  char* XB = alloc((size_t)M_NODES*512);
  char* G  = alloc((size_t)M_NODES*512);
  float* xF = (float*)alloc((size_t)M_NODES*64*4);
  float* pp = (float*)alloc((size_t)64*8*64*4);
  char* zbase = p;                       // contiguous zero-init region
  int* cnt  = (int*)alloc((size_t)M_NODES*4);
  int* cur  = (int*)alloc((size_t)M_NODES*4);
  int* gcnt = (int*)alloc(256);
  size_t zbytes = (size_t)(p - zbase);
  int* rp   = (int*)alloc((size_t)(M_NODES+1)*4);
  int* col  = (int*)alloc((size_t)E_EDGES*4);
  int* bsum = (int*)alloc((size_t)SCAN_B*4);
  int* boff = (int*)alloc((size_t)SCAN_B*4);
  unsigned short* W0h = (unsigned short*)alloc(128*256*2);
  unsigned short* W0l = (unsigned short*)alloc(128*256*2);
  unsigned short* W1h = (unsigned short*)alloc(128*256*2);
  unsigned short* W1l = (unsigned short*)alloc(128*256*2);
  unsigned short* W2h = (unsigned short*)alloc(128*256*2);
  unsigned short* W2l = (unsigned short*)alloc(128*256*2);
  unsigned short* L0h = (unsigned short*)alloc(128*128*2);
  unsigned short* L0l = (unsigned short*)alloc(128*128*2);
  unsigned short* L1h = (unsigned short*)alloc(128*128*2);
  unsigned short* L1l = (unsigned short*)alloc(128*128*2);
  unsigned short* L2h = (unsigned short*)alloc(64*128*2);
  unsigned short* L2l = (unsigned short*)alloc(64*128*2);

  hipMemsetAsync(zbase, 0, zbytes, stream);
  k_prep_all<<<544, 256, 0, stream>>>(ws0, wn0, ws1, wn1, ws2, wn2, lw0, lw1, lw2,
      W0h, W0l, W1h, W1l, W2h, W2l, L0h, L0l, L1h, L1l, L2h, L2l);
  k_split<<<(M_NODES*16 + 255)/256, 256, 0, stream>>>(h, X0);
  k_hist<<<(E_EDGES+255)/256, 256, 0, stream>>>(edst, cnt);
  k_scan1<<<SCAN_B, 256, 0, stream>>>(cnt, rp, bsum);
  k_scan2<<<1, 256, 0, stream>>>(bsum, boff);
  k_scan3<<<SCAN_B, 256, 0, stream>>>(rp, boff);
  k_fill<<<(E_EDGES+255)/256, 256, 0, stream>>>(esrc, edst, rp, cur, col);
  k_hist_gid<<<(M_NODES+255)/256, 256, 0, stream>>>(gid, gcnt);

  const int gGrid = (M_NODES + 127)/128;
  const int aGrid = (M_NODES + 7)/8;
  // SAGE layer 0 (relu)
  k_agg<<<aGrid, 256, 0, stream>>>(X0, rp, col, G);
  k_gemm<256,8,true ,true ><<<gGrid,256,0,stream>>>(X0, G, W0h, W0l, bs0, XA);
  // SAGE layer 1 (relu)
  k_agg<<<aGrid, 256, 0, stream>>>(XA, rp, col, G);
  k_gemm<256,8,true ,true ><<<gGrid,256,0,stream>>>(XA, G, W1h, W1l, bs1, XB);
  // SAGE layer 2 (no relu)
  k_agg<<<aGrid, 256, 0, stream>>>(XB, rp, col, G);
  k_gemm<256,8,false,true ><<<gGrid,256,0,stream>>>(XB, G, W2h, W2l, bs2, XA);
  // MLP
  k_gemm<128,8,true ,true ><<<gGrid,256,0,stream>>>(XA, nullptr, L0h, L0l, lb0, XB);
  k_gemm<128,8,true ,true ><<<gGrid,256,0,stream>>>(XB, nullptr, L1h, L1l, lb1, XA);
  k_gemm<128,4,false,false><<<gGrid,256,0,stream>>>(XA, nullptr, L2h, L2l, lb2, (char*)xF);
  // pooling
  k_pool1<<<512, 256, 0, stream>>>(xF, gcnt, pp);
  k_pool2<<<64, 64, 0, stream>>>(pp, gcnt, out);
}

// Round 5
// 305.019 us; speedup vs baseline: 1.8089x; 1.1943x over previous
//
#include <hip/hip_runtime.h>

#define M_NODES 50000
#define E_EDGES 600000
#define SCAN_B ((M_NODES + 255) / 256)

typedef short bf16x8 __attribute__((ext_vector_type(8)));
typedef float f32x4 __attribute__((ext_vector_type(4)));

__device__ __forceinline__ unsigned short f2bf(float f){
  unsigned u = __float_as_uint(f);
  u += 0x7FFFu + ((u >> 16) & 1u);
  return (unsigned short)(u >> 16);
}
__device__ __forceinline__ float bf2f(unsigned short h){
  return __uint_as_float(((unsigned)h) << 16);
}
__device__ __forceinline__ unsigned short lob(float x){
  unsigned short h = f2bf(x);
  return f2bf(x - bf2f(h));
}
__device__ __forceinline__ void gl_lds16(const void* g, void* l){
  __builtin_amdgcn_global_load_lds(
      (const __attribute__((address_space(1))) unsigned int*)g,
      (__attribute__((address_space(3))) unsigned int*)l, 16, 0, 0);
}

// ---------- split fp32 h -> split rows [hi128|lo128] ----------
__global__ __launch_bounds__(256) void k_split(const float* __restrict__ H,
    char* __restrict__ X){
  int i = blockIdx.x*256 + threadIdx.x;          // over M*16 granules
  if (i >= M_NODES*16) return;
  int n = i >> 4, j = i & 15;
  const float4 f0 = *reinterpret_cast<const float4*>(H + (size_t)n*128 + j*8);
  const float4 f1 = *reinterpret_cast<const float4*>(H + (size_t)n*128 + j*8 + 4);
  uint4 hq, lq;
  hq.x = (unsigned)f2bf(f0.x) | ((unsigned)f2bf(f0.y) << 16);
  hq.y = (unsigned)f2bf(f0.z) | ((unsigned)f2bf(f0.w) << 16);
  hq.z = (unsigned)f2bf(f1.x) | ((unsigned)f2bf(f1.y) << 16);
  hq.w = (unsigned)f2bf(f1.z) | ((unsigned)f2bf(f1.w) << 16);
  lq.x = (unsigned)lob(f0.x) | ((unsigned)lob(f0.y) << 16);
  lq.y = (unsigned)lob(f0.z) | ((unsigned)lob(f0.w) << 16);
  lq.z = (unsigned)lob(f1.x) | ((unsigned)lob(f1.y) << 16);
  lq.w = (unsigned)lob(f1.z) | ((unsigned)lob(f1.w) << 16);
  *reinterpret_cast<uint4*>(X + (size_t)n*512 + j*16)       = hq;
  *reinterpret_cast<uint4*>(X + (size_t)n*512 + 256 + j*16) = lq;
}

// ---------- all weight preps in one kernel ----------
__global__ __launch_bounds__(256) void k_prep_all(
    const float* __restrict__ ws0, const float* __restrict__ wn0,
    const float* __restrict__ ws1, const float* __restrict__ wn1,
    const float* __restrict__ ws2, const float* __restrict__ wn2,
    const float* __restrict__ lw0, const float* __restrict__ lw1,
    const float* __restrict__ lw2,
    unsigned short* __restrict__ W0h, unsigned short* __restrict__ W0l,
    unsigned short* __restrict__ W1h, unsigned short* __restrict__ W1l,
    unsigned short* __restrict__ W2h, unsigned short* __restrict__ W2l,
    unsigned short* __restrict__ L0h, unsigned short* __restrict__ L0l,
    unsigned short* __restrict__ L1h, unsigned short* __restrict__ L1l,
    unsigned short* __restrict__ L2h, unsigned short* __restrict__ L2l){
  const int b = blockIdx.x, t = threadIdx.x;
  if (b < 384){                      // stacked [ws;wn] -> [N=128][K=256]
    const int wsel = b >> 7;
    const int i = (b & 127)*256 + t;
    const float* Wa = wsel==0?ws0:(wsel==1?ws1:ws2);
    const float* Wb = wsel==0?wn0:(wsel==1?wn1:wn2);
    unsigned short* Th = wsel==0?W0h:(wsel==1?W1h:W2h);
    unsigned short* Tl = wsel==0?W0l:(wsel==1?W1l:W2l);
    int n = i >> 8, k = i & 255;
    float v = (k < 128) ? Wa[k*128 + n] : Wb[(k-128)*128 + n];
    unsigned short hi = f2bf(v);
    Th[n*256 + k] = hi; Tl[n*256 + k] = f2bf(v - bf2f(hi));
  } else if (b < 512){               // lw0/lw1 [128][128] -> [128][128]^T
    const int lsel = (b - 384) >> 6;
    const int i = ((b - 384) & 63)*256 + t;
    const float* W = lsel==0?lw0:lw1;
    unsigned short* Th = lsel==0?L0h:L1h;
    unsigned short* Tl = lsel==0?L0l:L1l;
    int n = i >> 7, k = i & 127;
    float v = W[k*128 + n];
    unsigned short hi = f2bf(v);
    Th[n*128 + k] = hi; Tl[n*128 + k] = f2bf(v - bf2f(hi));
  } else {                           // lw2 [128][64] -> [64][128]^T
    const int i = (b - 512)*256 + t;
    if (i >= 64*128) return;
    int n = i >> 7, k = i & 127;
    float v = lw2[k*64 + n];
    unsigned short hi = f2bf(v);
    L2h[n*128 + k] = hi; L2l[n*128 + k] = f2bf(v - bf2f(hi));
  }
}

// ---------- degree histogram + graph-id histogram (fused) ----------
__global__ __launch_bounds__(256) void k_hist(const int* __restrict__ dst, int* __restrict__ cnt,
    const int* __restrict__ gid, int* __restrict__ gcnt){
  int i = blockIdx.x*256 + threadIdx.x;
  if (i < E_EDGES) atomicAdd(&cnt[dst[i]], 1);
  if (i < M_NODES){
    int g = gid[i];
    int g0 = __shfl(g, 0);
    bool lastblk = (i | 63) >= M_NODES - 1 && ((i | 63) != M_NODES - 1);
    if (__all(g == g0) && !lastblk){
      if ((threadIdx.x & 63) == 0) atomicAdd(&gcnt[g], min(64, M_NODES - (i & ~63)));
    } else {
      atomicAdd(&gcnt[g], 1);
    }
  }
}

// ---------- 3-phase exclusive scan of cnt -> rp ----------
__global__ __launch_bounds__(256) void k_scan1(const int* __restrict__ cnt,
    int* __restrict__ rp, int* __restrict__ bsum){
  __shared__ int wsum[4];
  int b = blockIdx.x, tid = threadIdx.x, lane = tid & 63, w = tid >> 6;
  int i = b*256 + tid;
  int v = (i < M_NODES) ? cnt[i] : 0;
  int x = v;
  #pragma unroll
  for (int off = 1; off < 64; off <<= 1){
    int y = __shfl_up(x, off);
    if (lane >= off) x += y;
  }
  if (lane == 63) wsum[w] = x;
  __syncthreads();
  int pre = 0;
  #pragma unroll
  for (int j = 0; j < 4; j++) if (j < w) pre += wsum[j];
  if (i < M_NODES) rp[i+1] = pre + x;
  if (tid == 255) bsum[b] = pre + x;
}

__global__ __launch_bounds__(256) void k_scan2(const int* __restrict__ bsum, int* __restrict__ boff){
  __shared__ int wsum[4];
  int tid = threadIdx.x, lane = tid & 63, w = tid >> 6;
  int v = (tid < SCAN_B) ? bsum[tid] : 0;
  int x = v;
  #pragma unroll
  for (int off = 1; off < 64; off <<= 1){
    int y = __shfl_up(x, off);
    if (lane >= off) x += y;
  }
  if (lane == 63) wsum[w] = x;
  __syncthreads();
  int pre = 0;
  #pragma unroll
  for (int j = 0; j < 4; j++) if (j < w) pre += wsum[j];
  if (tid < SCAN_B) boff[tid] = pre + x - v;
}

__global__ __launch_bounds__(256) void k_scan3(int* __restrict__ rp, const int* __restrict__ boff){
  int b = blockIdx.x, tid = threadIdx.x;
  int i = b*256 + tid;
  if (i == 0) rp[0] = 0;
  if (i < M_NODES) rp[i+1] += boff[b];
}

// ---------- CSR fill ----------
__global__ __launch_bounds__(256) void k_fill(const int* __restrict__ src,
    const int* __restrict__ dst, const int* __restrict__ rp,
    int* __restrict__ cur, int* __restrict__ col){
  int e = blockIdx.x*256 + threadIdx.x;
  if (e >= E_EDGES) return;
  int d = dst[e];
  int pos = rp[d] + atomicAdd(&cur[d], 1);
  col[pos] = src[e];
}

// ---------- mean aggregation, hi-only gather (256B/row), quarter-wave per node ----------
#define ACC8(u) \
  a[0] += __uint_as_float((u).x << 16); a[1] += __uint_as_float((u).x & 0xFFFF0000u); \
  a[2] += __uint_as_float((u).y << 16); a[3] += __uint_as_float((u).y & 0xFFFF0000u); \
  a[4] += __uint_as_float((u).z << 16); a[5] += __uint_as_float((u).z & 0xFFFF0000u); \
  a[6] += __uint_as_float((u).w << 16); a[7] += __uint_as_float((u).w & 0xFFFF0000u);

__global__ __launch_bounds__(256) void k_agg(const char* __restrict__ X,
    const int* __restrict__ rp, const int* __restrict__ col, char* __restrict__ G){
  const int q  = threadIdx.x >> 4;          // 16 quarters per block
  const int ql = threadIdx.x & 15;
  const int v = blockIdx.x*16 + q;
  if (v >= M_NODES) return;
  const int beg = rp[v], end = rp[v+1];
  const int off = ql*16;
  float a[8];
  #pragma unroll
  for (int k = 0; k < 8; k++) a[k] = 0.f;
  int e = beg;
  for (; e + 4 <= end; e += 4){
    const int s0 = col[e], s1 = col[e+1], s2 = col[e+2], s3 = col[e+3];
    const uint4 x0 = *reinterpret_cast<const uint4*>(X + (size_t)s0*512 + off);
    const uint4 x1 = *reinterpret_cast<const uint4*>(X + (size_t)s1*512 + off);
    const uint4 x2 = *reinterpret_cast<const uint4*>(X + (size_t)s2*512 + off);
    const uint4 x3 = *reinterpret_cast<const uint4*>(X + (size_t)s3*512 + off);
    ACC8(x0); ACC8(x1); ACC8(x2); ACC8(x3);
  }
  for (; e < end; e++){
    const uint4 x0 = *reinterpret_cast<const uint4*>(X + (size_t)col[e]*512 + off);
    ACC8(x0);
  }
  const float inv = 1.f / fmaxf((float)(end - beg), 1.f);
  uint4 hq, lq;
  unsigned hw[4], lw[4];
  #pragma unroll
  for (int k = 0; k < 4; k++){
    const float x0 = a[2*k]*inv, x1 = a[2*k+1]*inv;
    const unsigned short h0 = f2bf(x0), h1 = f2bf(x1);
    hw[k] = (unsigned)h0 | ((unsigned)h1 << 16);
    lw[k] = (unsigned)f2bf(x0 - bf2f(h0)) | ((unsigned)f2bf(x1 - bf2f(h1)) << 16);
  }
  hq.x = hw[0]; hq.y = hw[1]; hq.z = hw[2]; hq.w = hw[3];
  lq.x = lw[0]; lq.y = lw[1]; lq.z = lw[2]; lq.w = lw[3];
  *reinterpret_cast<uint4*>(G + (size_t)v*512 + off)       = hq;
  *reinterpret_cast<uint4*>(G + (size_t)v*512 + 256 + off) = lq;
}

// ---------- GEMM: split-row A (global_load_lds), split W, bf16x3 ----------
template<int KL, int NT, bool RELU, bool SPLITOUT>
__global__ __launch_bounds__(256) void k_gemm(
    const char* __restrict__ A1, const char* __restrict__ A2,
    const unsigned short* __restrict__ Wh, const unsigned short* __restrict__ Wl,
    const float* __restrict__ bias, char* __restrict__ Y){
  constexpr int NOUT = NT * 16;
  constexpr int KC = KL / 64;
  constexpr int NBI = NOUT / 32;           // B stage insts per wave
  __shared__ __align__(16) char sAh[128*128];
  __shared__ __align__(16) char sAl[128*128];
  __shared__ __align__(16) char sBh[NOUT*128];
  __shared__ __align__(16) char sBl[NOUT*128];
  const int tid = threadIdx.x;
  const int wave = tid >> 6, lane = tid & 63;
  const int blockRow = blockIdx.x * 128;
  const int srow = lane >> 3, slot = lane & 7;
  const int sb = (slot*16) ^ (srow << 4);  // inverse-swizzled source granule
  size_t aoff[4];
  #pragma unroll
  for (int i = 0; i < 4; i++){
    int grow = blockRow + wave*32 + i*8 + srow;
    if (grow >= M_NODES) grow = M_NODES - 1;
    aoff[i] = (size_t)grow*512 + sb;
  }
  size_t boff[NBI];
  #pragma unroll
  for (int i = 0; i < NBI; i++){
    int n = wave*(NOUT/4) + i*8 + srow;
    boff[i] = (size_t)n*(2*KL) + sb;
  }
  f32x4 acc[2][NT];
  #pragma unroll
  for (int a = 0; a < 2; a++)
    #pragma unroll
    for (int i = 0; i < NT; i++)
      #pragma unroll
      for (int r = 0; r < 4; r++) acc[a][i][r] = 0.f;

  for (int kc = 0; kc < KC; kc++){
    const char* Ap; int acolb;
    if (KL == 256 && kc >= 2){ Ap = A2; acolb = (kc - 2)*128; }
    else                     { Ap = A1; acolb = kc*128; }
    const int bcolb = kc*128;
    __syncthreads();
    #pragma unroll
    for (int i = 0; i < 4; i++){
      const int lr = (wave*32 + i*8)*128;
      gl_lds16(Ap + aoff[i] + acolb,       sAh + lr);
      gl_lds16(Ap + aoff[i] + acolb + 256, sAl + lr);
    }
    #pragma unroll
    for (int i = 0; i < NBI; i++){
      const int lr = (wave*(NOUT/4) + i*8)*128;
      gl_lds16(reinterpret_cast<const char*>(Wh) + boff[i] + bcolb, sBh + lr);
      gl_lds16(reinterpret_cast<const char*>(Wl) + boff[i] + bcolb, sBl + lr);
    }
    __syncthreads();
    #pragma unroll
    for (int ks = 0; ks < 2; ks++){
      const int kb = (ks*32 + ((lane >> 4) * 8)) * 2;
      bf16x8 ah[2], al[2];
      #pragma unroll
      for (int ar = 0; ar < 2; ar++){
        const int arow = wave*32 + ar*16 + (lane & 15);
        const int ab = arow*128 + (kb ^ ((arow & 7) << 4));
        ah[ar] = *reinterpret_cast<const bf16x8*>(sAh + ab);
        al[ar] = *reinterpret_cast<const bf16x8*>(sAl + ab);
      }
      #pragma unroll
      for (int nt = 0; nt < NT; nt++){
        const int n = nt*16 + (lane & 15);
        const int bb = n*128 + (kb ^ ((n & 7) << 4));
        const bf16x8 bh = *reinterpret_cast<const bf16x8*>(sBh + bb);
        const bf16x8 bl = *reinterpret_cast<const bf16x8*>(sBl + bb);
        #pragma unroll
        for (int ar = 0; ar < 2; ar++){
          acc[ar][nt] = __builtin_amdgcn_mfma_f32_16x16x32_bf16(ah[ar], bh, acc[ar][nt], 0, 0, 0);
          acc[ar][nt] = __builtin_amdgcn_mfma_f32_16x16x32_bf16(al[ar], bh, acc[ar][nt], 0, 0, 0);
          acc[ar][nt] = __builtin_amdgcn_mfma_f32_16x16x32_bf16(ah[ar], bl, acc[ar][nt], 0, 0, 0);
        }
      }
    }
  }
  // epilogue: row = (lane>>4)*4 + r, col = lane&15
  const int r0 = (lane >> 4) * 4;
  #pragma unroll
  for (int ar = 0; ar < 2; ar++){
    const int growb = blockRow + wave*32 + ar*16 + r0;
    #pragma unroll
    for (int nt = 0; nt < NT; nt++){
      const int colx = nt*16 + (lane & 15);
      const float bsv = bias[colx];
      #pragma unroll
      for (int r = 0; r < 4; r++){
        const int grow = growb + r;
        float vv = acc[ar][nt][r] + bsv;
        if (RELU) vv = fmaxf(vv, 0.f);
        if constexpr (SPLITOUT){
          const float vo = __shfl_xor(vv, 1);
          if (grow < M_NODES){
            if ((lane & 1) == 0){
              const unsigned hv = (unsigned)f2bf(vv) | ((unsigned)f2bf(vo) << 16);
              *reinterpret_cast<unsigned*>(Y + (size_t)grow*512 + colx*2) = hv;
            } else {
              const unsigned lv = (unsigned)lob(vo) | ((unsigned)lob(vv) << 16);
              *reinterpret_cast<unsigned*>(Y + (size_t)grow*512 + 256 + (colx-1)*2) = lv;
            }
          }
        } else {
          if (grow < M_NODES)
            *reinterpret_cast<float*>(Y + ((size_t)grow*NOUT + colx)*4) = vv;
        }
      }
    }
  }
}

// ---------- pooling stage 1: 8 sub-chunks per graph ----------
__global__ __launch_bounds__(256) void k_pool1(const float* __restrict__ Xf,
    const int* __restrict__ gcnt, float* __restrict__ pp){
  const int g = blockIdx.x >> 3, s = blockIdx.x & 7;
  const int tid = threadIdx.x, w = tid >> 6, lane = tid & 63;
  __shared__ int sstart;
  __shared__ float part[4][64];
  if (w == 0){
    int v = gcnt[lane];
    int x = v;
    #pragma unroll
    for (int off = 1; off < 64; off <<= 1){
      int y = __shfl_up(x, off);
      if (lane >= off) x += y;
    }
    if (lane == g) sstart = x - v;
  }
  __syncthreads();
  const int cg = gcnt[g];
  const int Lc = (cg + 7) >> 3;
  const int nbeg = sstart + s*Lc;
  const int nend = min(nbeg + Lc, sstart + cg);
  float a0 = 0.f, a1 = 0.f;
  int i = nbeg + w;
  for (; i + 4 < nend; i += 8){
    a0 += Xf[(size_t)i*64 + lane];
    a1 += Xf[(size_t)(i+4)*64 + lane];
  }
  if (i < nend) a0 += Xf[(size_t)i*64 + lane];
  part[w][lane] = a0 + a1;
  __syncthreads();
  if (w == 0)
    pp[(size_t)(g*8 + s)*64 + lane] = part[0][lane] + part[1][lane] + part[2][lane] + part[3][lane];
}

// ---------- pooling stage 2 ----------
__global__ __launch_bounds__(64) void k_pool2(const float* __restrict__ pp,
    const int* __restrict__ gcnt, float* __restrict__ out){
  const int g = blockIdx.x, lane = threadIdx.x;
  float sum = 0.f;
  #pragma unroll
  for (int s = 0; s < 8; s++) sum += pp[(size_t)(g*8 + s)*64 + lane];
  out[g*64 + lane] = sum / fmaxf((float)gcnt[g], 1.f);
}

extern "C" void kernel_launch(void* const* d_in, const int* in_sizes, int n_in,
                              void* d_out, int out_size, void* d_ws, size_t ws_size,
                              hipStream_t stream){
  const float* h    = (const float*)d_in[0];
  const int*   esrc = (const int*)d_in[1];
  const int*   edst = (const int*)d_in[2];
  const int*   gid  = (const int*)d_in[3];
  const float* ws0  = (const float*)d_in[4];
  const float* wn0  = (const float*)d_in[5];
  const float* bs0  = (const float*)d_in[6];
  const float* ws1  = (const float*)d_in[7];
  const float* wn1  = (const float*)d_in[8];
  const float* bs1  = (const float*)d_in[9];
  const float* ws2  = (const float*)d_in[10];
  const float* wn2  = (const float*)d_in[11];
  const float* bs2  = (const float*)d_in[12];
  const float* lw0  = (const float*)d_in[13];
  const float* lb0  = (const float*)d_in[14];
  const float* lw1  = (const float*)d_in[15];
  const float* lb1  = (const float*)d_in[16];
  const float* lw2  = (const float*)d_in[17];
  const float* lb2  = (const float*)d_in[18];
  float* out = (float*)d_out;

  char* p = (char*)d_ws;
  auto alloc = [&](size_t b)->char*{ char* r = p; p += (b + 255) & ~(size_t)255; return r; };
  char* X0 = alloc((size_t)M_NODES*512);
  char* XA = alloc((size_t)M_NODES*512);
  char* XB = alloc((size_t)M_NODES*512);
  char* G  = alloc((size_t)M_NODES*512);
  float* xF = (float*)alloc((size_t)M_NODES*64*4);
  float* pp = (float*)alloc((size_t)64*8*64*4);
  char* zbase = p;                       // contiguous zero-init region
  int* cnt  = (int*)alloc((size_t)M_NODES*4);
  int* cur  = (int*)alloc((size_t)M_NODES*4);
  int* gcnt = (int*)alloc(256);
  size_t zbytes = (size_t)(p - zbase);
  int* rp   = (int*)alloc((size_t)(M_NODES+1)*4);
  int* col  = (int*)alloc((size_t)E_EDGES*4);
  int* bsum = (int*)alloc((size_t)SCAN_B*4);
  int* boff = (int*)alloc((size_t)SCAN_B*4);
  unsigned short* W0h = (unsigned short*)alloc(128*256*2);
  unsigned short* W0l = (unsigned short*)alloc(128*256*2);
  unsigned short* W1h = (unsigned short*)alloc(128*256*2);
  unsigned short* W1l = (unsigned short*)alloc(128*256*2);
  unsigned short* W2h = (unsigned short*)alloc(128*256*2);
  unsigned short* W2l = (unsigned short*)alloc(128*256*2);
  unsigned short* L0h = (unsigned short*)alloc(128*128*2);
  unsigned short* L0l = (unsigned short*)alloc(128*128*2);
  unsigned short* L1h = (unsigned short*)alloc(128*128*2);
  unsigned short* L1l = (unsigned short*)alloc(128*128*2);
  unsigned short* L2h = (unsigned short*)alloc(64*128*2);
  unsigned short* L2l = (unsigned short*)alloc(64*128*2);

  hipMemsetAsync(zbase, 0, zbytes, stream);
  k_prep_all<<<544, 256, 0, stream>>>(ws0, wn0, ws1, wn1, ws2, wn2, lw0, lw1, lw2,
      W0h, W0l, W1h, W1l, W2h, W2l, L0h, L0l, L1h, L1l, L2h, L2l);
  k_split<<<(M_NODES*16 + 255)/256, 256, 0, stream>>>(h, X0);
  k_hist<<<(E_EDGES+255)/256, 256, 0, stream>>>(edst, cnt, gid, gcnt);
  k_scan1<<<SCAN_B, 256, 0, stream>>>(cnt, rp, bsum);
  k_scan2<<<1, 256, 0, stream>>>(bsum, boff);
  k_scan3<<<SCAN_B, 256, 0, stream>>>(rp, boff);
  k_fill<<<(E_EDGES+255)/256, 256, 0, stream>>>(esrc, edst, rp, cur, col);

  const int gGrid = (M_NODES + 127)/128;
  const int aGrid = (M_NODES + 15)/16;
  // SAGE layer 0 (relu)
  k_agg<<<aGrid, 256, 0, stream>>>(X0, rp, col, G);
  k_gemm<256,8,true ,true ><<<gGrid,256,0,stream>>>(X0, G, W0h, W0l, bs0, XA);
  // SAGE layer 1 (relu)
  k_agg<<<aGrid, 256, 0, stream>>>(XA, rp, col, G);
  k_gemm<256,8,true ,true ><<<gGrid,256,0,stream>>>(XA, G, W1h, W1l, bs1, XB);
  // SAGE layer 2 (no relu)
  k_agg<<<aGrid, 256, 0, stream>>>(XB, rp, col, G);
  k_gemm<256,8,false,true ><<<gGrid,256,0,stream>>>(XB, G, W2h, W2l, bs2, XA);
  // MLP
  k_gemm<128,8,true ,true ><<<gGrid,256,0,stream>>>(XA, nullptr, L0h, L0l, lb0, XB);
  k_gemm<128,8,true ,true ><<<gGrid,256,0,stream>>>(XB, nullptr, L1h, L1l, lb1, XA);
  k_gemm<128,4,false,false><<<gGrid,256,0,stream>>>(XA, nullptr, L2h, L2l, lb2, (char*)xF);
  // pooling
  k_pool1<<<512, 256, 0, stream>>>(xF, gcnt, pp);
  k_pool2<<<64, 64, 0, stream>>>(pp, gcnt, out);
}